// Round 2
// baseline (282.853 us; speedup 1.0000x reference)
//
#include <hip/hip_runtime.h>
#include <cstdint>

#define NN 2048
#define DD 128
#define BATCH 8
#define NROWS 16384
#define MARGIN 0.02f     // rigorous need: 2E + 2*bf16-half-ulp = 0.008 + 0.004 = 0.012
#define CAP 64

typedef __attribute__((ext_vector_type(8))) short bf16x8;
typedef __attribute__((ext_vector_type(4))) float f32x4;
typedef unsigned long long u64;
typedef unsigned int u32;
typedef unsigned short u16;

__device__ __forceinline__ u32 bf16rne(float f) {
  u32 u = __float_as_uint(f);
  return (u + 0x7fffu + ((u >> 16) & 1u)) >> 16;
}

// ---------------- K0: named zero-fill (replaces hipMemsetAsync; visible in profile) ----------------
__global__ __launch_bounds__(256) void k_zero(float4* __restrict__ out, int n4) {
  int i = blockIdx.x * 256 + threadIdx.x;
  const int stride = gridDim.x * 256;
  const float4 z = {0.0f, 0.0f, 0.0f, 0.0f};
  for (; i < n4; i += stride) out[i] = z;
}

// ---------------- K1: norms + bf16 normalized copy (validated R14-R17) ----------------
__global__ __launch_bounds__(256) void k_normalize(const float* __restrict__ x,
                                                   double* __restrict__ rinv,
                                                   u32* __restrict__ nb) {
  const int wave = threadIdx.x >> 6, lane = threadIdx.x & 63;
  const long long row = (long long)blockIdx.x * 4 + wave;   // 16384 rows
  float2 v = ((const float2*)(x + row * DD))[lane];
  const double d0 = v.x, d1 = v.y;
  double s = d0 * d0 + d1 * d1;
  #pragma unroll
  for (int m = 32; m >= 1; m >>= 1) s += __shfl_xor(s, m, 64);
  double den = sqrt(s); den = den > 1e-12 ? den : 1e-12;
  if (lane == 0) rinv[row] = 1.0 / den;
  double2 o; o.x = d0 / den; o.y = d1 / den;
  nb[row * (DD / 2) + lane] = bf16rne((float)o.x) | (bf16rne((float)o.y) << 16);
}

// ---------------- fp32 top-8 machinery: branch-free merge (validated R12/R18) ----------------
#define CXF(i, j) { const float a_ = L[i], b_ = L[j]; L[i] = fmaxf(a_, b_); L[j] = fminf(a_, b_); }
__device__ __forceinline__ void merge8f(float (&kv)[8], const float (&ov)[8]) {
  float L[8];
  #pragma unroll
  for (int i = 0; i < 8; ++i) L[i] = fmaxf(kv[i], ov[7 - i]);
  CXF(0, 4) CXF(1, 5) CXF(2, 6) CXF(3, 7)
  CXF(0, 2) CXF(1, 3) CXF(4, 6) CXF(5, 7)
  CXF(0, 1) CXF(2, 3) CXF(4, 5) CXF(6, 7)
  #pragma unroll
  for (int i = 0; i < 8; ++i) kv[i] = L[i];
}

// ---------------- u64 exact-key machinery (validated R5-R17) ----------------
__device__ __forceinline__ u64 make_key(double s, int col) {
  u64 u = (u64)__double_as_longlong(s);
  const u64 m = (u64)((long long)u >> 63);
  u ^= (m | 0x8000000000000000ull);
  return (u & ~2047ull) | (u64)(2047 - col);
}
__device__ __forceinline__ u64 umax64(u64 a, u64 b) { return a > b ? a : b; }
__device__ __forceinline__ u64 umin64(u64 a, u64 b) { return a > b ? b : a; }
__device__ __forceinline__ void merge8(u64 (&kv)[8], const u64 (&ov)[8]) {
  u64 L[8];
  #pragma unroll
  for (int i = 0; i < 8; ++i) L[i] = umax64(kv[i], ov[7 - i]);
#define CX(i, j) { const u64 a_ = L[i], b_ = L[j]; L[i] = umax64(a_, b_); L[j] = umin64(a_, b_); }
  CX(0, 4) CX(1, 5) CX(2, 6) CX(3, 7)
  CX(0, 2) CX(1, 3) CX(4, 6) CX(5, 7)
  CX(0, 1) CX(2, 3) CX(4, 5) CX(6, 7)
#undef CX
  #pragma unroll
  for (int i = 0; i < 8; ++i) kv[i] = L[i];
}
__device__ __forceinline__ void insert8u(u64 (&v)[8], u64 nk) {
  if (nk > v[7]) {
    v[7] = nk;
    #pragma unroll
    for (int q = 7; q >= 1; --q) {
      const u64 a = v[q - 1], b = v[q];
      const bool sw = b > a;
      v[q - 1] = sw ? b : a; v[q] = sw ? a : b;
    }
  }
}

// ---------------- k_gram: bf16 Gram once, stream bf16 scores (validated R17) ----------------
__global__ __launch_bounds__(256) void k_gram(const u32* __restrict__ nb,
                                              u16* __restrict__ scores) {
  const int tid = threadIdx.x; const int w = tid >> 6; const int l = tid & 63;
  const int q = l >> 4; const int m = l & 15;
  bf16x8 pvals = {0,0,0,0,0,0,0,0}, pones = {0,0,0,0,0,0,0,0};
  if (q == 0) {
    pvals[0] = (short)(__float_as_uint((float)(m + 1)) >> 16);
    pones[0] = (short)(__float_as_uint(1.0f) >> 16);
  }
  const f32x4 z4 = {0.0f, 0.0f, 0.0f, 0.0f};
  const f32x4 pr  = __builtin_amdgcn_mfma_f32_16x16x32_bf16(pvals, pones, z4, 0, 0, 0);
  const f32x4 pr2 = __builtin_amdgcn_mfma_f32_16x16x32_bf16(pones, pvals, z4, 0, 0, 0);
  int cof[4];
  #pragma unroll
  for (int p = 0; p < 4; ++p) cof[p] = (int)pr[p] - 1;
  const int rof = (int)pr2[0] - 1;
  const bool contig = (cof[1] == cof[0] + 1) && (cof[2] == cof[0] + 2) &&
                      (cof[3] == cof[0] + 3) && ((cof[0] & 3) == 0);
  const int rowblk = blockIdx.x >> 2; const int split = blockIdx.x & 3;
  const int row0 = rowblk * 64 + 16 * w;
  const int b = rowblk >> 5; const int c0 = split * 512;
  const u32* Bb = nb + ((long long)b * NN + c0) * (DD / 2);
  bf16x8 ar[4];
  { const u32* Ap = nb + (long long)(row0 + m) * (DD / 2) + 4 * q;
    #pragma unroll
    for (int cc = 0; cc < 4; ++cc) ar[cc] = *(const bf16x8*)(Ap + 16 * cc); }
  bf16x8 bcA[4], bcB[4];
  u16* rowbase = scores + (long long)(row0 + rof) * NN + c0;

#define LOADB(DST, T) { const u32* p_ = Bb + (long long)(16 * (T) + m) * (DD / 2) + 4 * q; \
  _Pragma("unroll") for (int cc = 0; cc < 4; ++cc) DST[cc] = *(const bf16x8*)(p_ + 16 * cc); }
#define GEMM16(ACC, BC) { ACC = z4;                                                \
  _Pragma("unroll") for (int cc = 0; cc < 4; ++cc)                                 \
    ACC = __builtin_amdgcn_mfma_f32_16x16x32_bf16(BC[cc], ar[cc], ACC, 0, 0, 0); }
#define STORE4(ACC, T) { u16* sp = rowbase + 16 * (T);                             \
    if (contig) {                                                                  \
      uint2 sv;                                                                    \
      sv.x = bf16rne(ACC[0]) | (bf16rne(ACC[1]) << 16);                            \
      sv.y = bf16rne(ACC[2]) | (bf16rne(ACC[3]) << 16);                            \
      *(uint2*)(sp + cof[0]) = sv;                                                 \
    } else {                                                                       \
      sp[cof[0]] = (u16)bf16rne(ACC[0]); sp[cof[1]] = (u16)bf16rne(ACC[1]);        \
      sp[cof[2]] = (u16)bf16rne(ACC[2]); sp[cof[3]] = (u16)bf16rne(ACC[3]);        \
    } }

  LOADB(bcA, 0)
  for (int t = 0; t < 32; t += 2) {
    LOADB(bcB, t + 1)
    { f32x4 acc; GEMM16(acc, bcA) STORE4(acc, t) }
    if (t + 2 < 32) LOADB(bcA, t + 2)
    { f32x4 acc; GEMM16(acc, bcB) STORE4(acc, t + 1) }
  }
#undef LOADB
#undef GEMM16
#undef STORE4
}

// ---------------- k_topk_exact: fused theta + survivors + fp64 rescore ----------------
// R19: threshold from 8th-largest LANE-MAX (m8 <= v8 => survivor superset; exact fp64
//      rescore makes selection identical). Replaces the 32-value fold + dense butterfly
//      (~590 VALU) with lane-max tree + sparse 1->2->4->8 butterfly (~190 VALU).
__global__ __launch_bounds__(256) void k_topk_exact(const u16* __restrict__ scores,
                                                    const float* __restrict__ x,
                                                    const double* __restrict__ rinv,
                                                    float* __restrict__ out) {
  __shared__ u32 scnt[4];
  __shared__ u32 scand[4][CAP];

  const int w = threadIdx.x >> 6, l = threadIdx.x & 63;
  const int r = blockIdx.x * 4 + w;            // 0..16383
  const int n = r & (NN - 1);
  const long long brow = r - n;                // b*NN

  if (l == 0) scnt[w] = 0u;                    // wave-local; LDS in-order, no barrier

  // load the row's 2048 bf16 scores: 4 x uint4 = 32 scores/lane, coalesced
  const u32* row32 = (const u32*)(scores + (long long)r * NN);
  uint4 rv[4];
  #pragma unroll
  for (int i = 0; i < 4; ++i) rv[i] = ((const uint4*)row32)[i * 64 + l];

  float fs[32];
  #pragma unroll
  for (int i = 0; i < 4; ++i)
    #pragma unroll
    for (int c = 0; c < 4; ++c) {
      const u32 u = (&rv[i].x)[c];
      fs[i * 8 + 2 * c]     = __uint_as_float(u << 16);
      fs[i * 8 + 2 * c + 1] = __uint_as_float(u & 0xFFFF0000u);
    }

  // ---- lane max (tree, 31 fmax) ----
  float t16[16];
  #pragma unroll
  for (int i = 0; i < 16; ++i) t16[i] = fmaxf(fs[i], fs[i + 16]);
  #pragma unroll
  for (int i = 0; i < 8; ++i) t16[i] = fmaxf(t16[i], t16[i + 8]);
  #pragma unroll
  for (int i = 0; i < 4; ++i) t16[i] = fmaxf(t16[i], t16[i + 4]);
  float mx = fmaxf(fmaxf(t16[0], t16[1]), fmaxf(t16[2], t16[3]));

  // ---- sparse butterfly: top-8 of the 64 lane-maxes, all lanes converge ----
  float kv8[8];
  {
    // S1 (xor 1): 1+1 -> sorted 2
    const float o  = __shfl_xor(mx, 1, 64);
    const float h2 = fmaxf(mx, o), l2 = fminf(mx, o);
    // S2 (xor 2): 2+2 -> sorted 4
    const float p0 = __shfl_xor(h2, 2, 64), p1 = __shfl_xor(l2, 2, 64);
    const float m0 = fmaxf(h2, p0);
    const float xx = fminf(h2, p0);
    const float yy = fmaxf(l2, p1);
    const float m3 = fminf(l2, p1);
    const float m1 = fmaxf(xx, yy);
    const float m2 = fminf(xx, yy);
    // S3 (xor 4): 4+4 -> sorted 8 (desc ++ reversed-desc = bitonic; 12-CEX merge)
    const float q0 = __shfl_xor(m0, 4, 64), q1 = __shfl_xor(m1, 4, 64);
    const float q2 = __shfl_xor(m2, 4, 64), q3 = __shfl_xor(m3, 4, 64);
    float L[8] = {m0, m1, m2, m3, q3, q2, q1, q0};
    CXF(0, 4) CXF(1, 5) CXF(2, 6) CXF(3, 7)
    CXF(0, 2) CXF(1, 3) CXF(4, 6) CXF(5, 7)
    CXF(0, 1) CXF(2, 3) CXF(4, 5) CXF(6, 7)
    #pragma unroll
    for (int s = 0; s < 8; ++s) kv8[s] = L[s];
    // S4-S6 (xor 8,16,32): full sorted-8 merges
    #pragma unroll
    for (int mk = 8; mk <= 32; mk <<= 1) {
      float ov[8];
      #pragma unroll
      for (int s = 0; s < 8; ++s) ov[s] = __shfl_xor(kv8[s], mk, 64);
      merge8f(kv8, ov);
    }
  }
  const float th = kv8[7] - MARGIN;            // m8 - margin <= v8 - margin: superset

  // push survivors into the wave's LDS buffer (~18/row expected)
  #pragma unroll
  for (int i = 0; i < 4; ++i)
    #pragma unroll
    for (int c = 0; c < 4; ++c) {
      const int colb = 8 * (i * 64 + l) + 2 * c;
      if (fs[i * 8 + 2 * c] >= th) {
        const u32 idx = atomicAdd(&scnt[w], 1u);
        if (idx < CAP) scand[w][idx] = (u32)colb;
      }
      if (fs[i * 8 + 2 * c + 1] >= th) {
        const u32 idx = atomicAdd(&scnt[w], 1u);
        if (idx < CAP) scand[w][idx] = (u32)(colb + 1);
      }
    }

  const int c = (int)scnt[w];                  // wave-lockstep: all pushes complete
  const float2 a2 = ((const float2*)(x + (long long)r * DD))[l];
  const double ri = rinv[r];
  u64 kv[8];
  #pragma unroll
  for (int s = 0; s < 8; ++s) kv[s] = 0ull;

  if (c <= CAP) {
    for (int i = 0; i < c; i += 4) {
      float2 vv[4]; int col[4];
      #pragma unroll
      for (int g = 0; g < 4; ++g) {
        const int idx = i + g;
        col[g] = (idx < c) ? ((int)scand[w][idx] & (NN - 1)) : 0;
        vv[g] = ((const float2*)(x + (brow + col[g]) * DD))[l];
      }
      #pragma unroll
      for (int g = 0; g < 4; ++g) {
        double d = fma((double)a2.x, (double)vv[g].x, (double)a2.y * (double)vv[g].y);
        #pragma unroll
        for (int mk = 1; mk <= 32; mk <<= 1) d += __shfl_xor(d, mk, 64);
        if (i + g < c) insert8u(kv, make_key(d * ri * rinv[brow + col[g]], col[g]));
      }
    }
  } else {
    // overflow fallback (never expected): full exact row scan (validated)
    for (int base = 0; base < NN; base += 64) {
      const int col = base + l;
      const float* ap = x + (long long)r * DD;
      const float* cp = x + (brow + col) * DD;
      double d = 0.0;
      for (int kk = 0; kk < 64; ++kk) {
        const float2 av = ((const float2*)ap)[kk];
        const float2 bv = ((const float2*)cp)[kk];
        d = fma((double)av.x, (double)bv.x, fma((double)av.y, (double)bv.y, d));
      }
      d = d * ri * rinv[brow + col];
      u64 one[8];
      one[0] = make_key(d, col);
      #pragma unroll
      for (int s = 1; s < 8; ++s) one[s] = 0ull;
      #pragma unroll
      for (int mk = 1; mk <= 32; mk <<= 1) {
        u64 ov[8];
        #pragma unroll
        for (int s = 0; s < 8; ++s) ov[s] = __shfl_xor(one[s], mk, 64);
        merge8(one, ov);
      }
      merge8(kv, one);
    }
  }

  const long long orow = (long long)r * NN;
  const long long obase = brow * NN;           // b*NN*NN
  if (l == 8) out[orow + n] = 1.0f;            // self loop
  #pragma unroll
  for (int s = 0; s < 8; ++s) {
    const int mcol = 2047 - (int)(kv[s] & 2047ull);
    if (l == s) {
      out[orow + mcol] = 1.0f;
      out[obase + (long long)mcol * NN + n] = 1.0f;
    }
  }
}

extern "C" void kernel_launch(void* const* d_in, const int* in_sizes, int n_in,
                              void* d_out, int out_size, void* d_ws, size_t ws_size,
                              hipStream_t stream) {
  const float* x = (const float*)d_in[0];
  float* out = (float*)d_out;
  char* ws = (char*)d_ws;
  u32* nb = (u32*)ws;                                //  4,194,304 B (bf16 normed)
  double* rinv = (double*)(ws + 4194304);            //    131,072 B
  u16* scores = (u16*)(ws + 4325376);                // 67,108,864 B (bf16 scores)

  hipLaunchKernelGGL(k_zero, dim3(4096), dim3(256), 0, stream,
                     (float4*)out, out_size / 4);
  hipLaunchKernelGGL(k_normalize, dim3(NROWS / 4), dim3(256), 0, stream, x, rinv, nb);
  hipLaunchKernelGGL(k_gram, dim3(1024), dim3(256), 0, stream, nb, scores);
  hipLaunchKernelGGL(k_topk_exact, dim3(NROWS / 4), dim3(256), 0, stream, scores, x, rinv, out);
}

// Round 3
// 270.747 us; speedup vs baseline: 1.0447x; 1.0447x over previous
//
#include <hip/hip_runtime.h>
#include <cstdint>

#define NN 2048
#define DD 128
#define BATCH 8
#define NROWS 16384
#define MARGIN 0.02f     // rigorous need: 2E + 2*bf16-half-ulp = 0.008 + 0.004 = 0.012
#define CAP 64

typedef __attribute__((ext_vector_type(8))) short bf16x8;
typedef __attribute__((ext_vector_type(4))) float f32x4;
typedef unsigned long long u64;
typedef unsigned int u32;
typedef unsigned short u16;

__device__ __forceinline__ u32 bf16rne(float f) {
  u32 u = __float_as_uint(f);
  return (u + 0x7fffu + ((u >> 16) & 1u)) >> 16;
}

// ---------------- K0: named zero-fill ----------------
__global__ __launch_bounds__(256) void k_zero(float4* __restrict__ out, int n4) {
  int i = blockIdx.x * 256 + threadIdx.x;
  const int stride = gridDim.x * 256;
  const float4 z = {0.0f, 0.0f, 0.0f, 0.0f};
  for (; i < n4; i += stride) out[i] = z;
}

// ---------------- K1: norms + bf16 normalized copy (validated R14-R17) ----------------
__global__ __launch_bounds__(256) void k_normalize(const float* __restrict__ x,
                                                   double* __restrict__ rinv,
                                                   u32* __restrict__ nb) {
  const int wave = threadIdx.x >> 6, lane = threadIdx.x & 63;
  const long long row = (long long)blockIdx.x * 4 + wave;   // 16384 rows
  float2 v = ((const float2*)(x + row * DD))[lane];
  const double d0 = v.x, d1 = v.y;
  double s = d0 * d0 + d1 * d1;
  #pragma unroll
  for (int m = 32; m >= 1; m >>= 1) s += __shfl_xor(s, m, 64);
  double den = sqrt(s); den = den > 1e-12 ? den : 1e-12;
  if (lane == 0) rinv[row] = 1.0 / den;
  double2 o; o.x = d0 / den; o.y = d1 / den;
  nb[row * (DD / 2) + lane] = bf16rne((float)o.x) | (bf16rne((float)o.y) << 16);
}

// ---------------- fp32 top-8 machinery: branch-free merge (validated R12/R18) ----------------
#define CXF(i, j) { const float a_ = L[i], b_ = L[j]; L[i] = fmaxf(a_, b_); L[j] = fminf(a_, b_); }
__device__ __forceinline__ void merge8f(float (&kv)[8], const float (&ov)[8]) {
  float L[8];
  #pragma unroll
  for (int i = 0; i < 8; ++i) L[i] = fmaxf(kv[i], ov[7 - i]);
  CXF(0, 4) CXF(1, 5) CXF(2, 6) CXF(3, 7)
  CXF(0, 2) CXF(1, 3) CXF(4, 6) CXF(5, 7)
  CXF(0, 1) CXF(2, 3) CXF(4, 5) CXF(6, 7)
  #pragma unroll
  for (int i = 0; i < 8; ++i) kv[i] = L[i];
}

// ---------------- u64 exact-key machinery (validated R5-R17) ----------------
__device__ __forceinline__ u64 make_key(double s, int col) {
  u64 u = (u64)__double_as_longlong(s);
  const u64 m = (u64)((long long)u >> 63);
  u ^= (m | 0x8000000000000000ull);
  return (u & ~2047ull) | (u64)(2047 - col);
}
__device__ __forceinline__ u64 umax64(u64 a, u64 b) { return a > b ? a : b; }
__device__ __forceinline__ u64 umin64(u64 a, u64 b) { return a > b ? b : a; }
__device__ __forceinline__ void merge8(u64 (&kv)[8], const u64 (&ov)[8]) {
  u64 L[8];
  #pragma unroll
  for (int i = 0; i < 8; ++i) L[i] = umax64(kv[i], ov[7 - i]);
#define CX(i, j) { const u64 a_ = L[i], b_ = L[j]; L[i] = umax64(a_, b_); L[j] = umin64(a_, b_); }
  CX(0, 4) CX(1, 5) CX(2, 6) CX(3, 7)
  CX(0, 2) CX(1, 3) CX(4, 6) CX(5, 7)
  CX(0, 1) CX(2, 3) CX(4, 5) CX(6, 7)
#undef CX
  #pragma unroll
  for (int i = 0; i < 8; ++i) kv[i] = L[i];
}
__device__ __forceinline__ void insert8u(u64 (&v)[8], u64 nk) {
  if (nk > v[7]) {
    v[7] = nk;
    #pragma unroll
    for (int q = 7; q >= 1; --q) {
      const u64 a = v[q - 1], b = v[q];
      const bool sw = b > a;
      v[q - 1] = sw ? b : a; v[q] = sw ? a : b;
    }
  }
}

// ---------------- k_gram: bf16 Gram + per-16-col block-max sideband ----------------
// bmax layout: bmaxg[(split*16384 + row)*32 + t]  (u16 bf16) -> block writes are one
// contiguous 4 KB region per workgroup; topk reads a row's 128 maxes as 4x64B segments.
// Row->lane mapping (gfx950 m89-verified: row=lane&15, cols=(lane>>4)*4+reg for the
// swapped-operand mfma): the 16 cols of row m live in lanes {m, m+16, m+32, m+48},
// so xor-16/32 shuffles reduce over the col groups. bf16rne is monotone, so
// rne(max(f32)) == max(rne(f32)) and threshold comparisons stay exact.
__global__ __launch_bounds__(256) void k_gram(const u32* __restrict__ nb,
                                              u16* __restrict__ scores,
                                              u16* __restrict__ bmaxg) {
  __shared__ u16 bml[4][16][40];   // [wave][row m][t] (+pad: stride 40 u16 -> 2-way max)
  const int tid = threadIdx.x; const int w = tid >> 6; const int l = tid & 63;
  const int q = l >> 4; const int m = l & 15;
  bf16x8 pvals = {0,0,0,0,0,0,0,0}, pones = {0,0,0,0,0,0,0,0};
  if (q == 0) {
    pvals[0] = (short)(__float_as_uint((float)(m + 1)) >> 16);
    pones[0] = (short)(__float_as_uint(1.0f) >> 16);
  }
  const f32x4 z4 = {0.0f, 0.0f, 0.0f, 0.0f};
  const f32x4 pr  = __builtin_amdgcn_mfma_f32_16x16x32_bf16(pvals, pones, z4, 0, 0, 0);
  const f32x4 pr2 = __builtin_amdgcn_mfma_f32_16x16x32_bf16(pones, pvals, z4, 0, 0, 0);
  int cof[4];
  #pragma unroll
  for (int p = 0; p < 4; ++p) cof[p] = (int)pr[p] - 1;
  const int rof = (int)pr2[0] - 1;
  const bool contig = (cof[1] == cof[0] + 1) && (cof[2] == cof[0] + 2) &&
                      (cof[3] == cof[0] + 3) && ((cof[0] & 3) == 0);
  const int rowblk = blockIdx.x >> 2; const int split = blockIdx.x & 3;
  const int row0 = rowblk * 64 + 16 * w;
  const int b = rowblk >> 5; const int c0 = split * 512;
  const u32* Bb = nb + ((long long)b * NN + c0) * (DD / 2);
  bf16x8 ar[4];
  { const u32* Ap = nb + (long long)(row0 + m) * (DD / 2) + 4 * q;
    #pragma unroll
    for (int cc = 0; cc < 4; ++cc) ar[cc] = *(const bf16x8*)(Ap + 16 * cc); }
  bf16x8 bcA[4], bcB[4];
  u16* rowbase = scores + (long long)(row0 + rof) * NN + c0;

#define LOADB(DST, T) { const u32* p_ = Bb + (long long)(16 * (T) + m) * (DD / 2) + 4 * q; \
  _Pragma("unroll") for (int cc = 0; cc < 4; ++cc) DST[cc] = *(const bf16x8*)(p_ + 16 * cc); }
#define GEMM16(ACC, BC) { ACC = z4;                                                \
  _Pragma("unroll") for (int cc = 0; cc < 4; ++cc)                                 \
    ACC = __builtin_amdgcn_mfma_f32_16x16x32_bf16(BC[cc], ar[cc], ACC, 0, 0, 0); }
#define STORE4(ACC, T) { u16* sp = rowbase + 16 * (T);                             \
    if (contig) {                                                                  \
      uint2 sv;                                                                    \
      sv.x = bf16rne(ACC[0]) | (bf16rne(ACC[1]) << 16);                            \
      sv.y = bf16rne(ACC[2]) | (bf16rne(ACC[3]) << 16);                            \
      *(uint2*)(sp + cof[0]) = sv;                                                 \
    } else {                                                                       \
      sp[cof[0]] = (u16)bf16rne(ACC[0]); sp[cof[1]] = (u16)bf16rne(ACC[1]);        \
      sp[cof[2]] = (u16)bf16rne(ACC[2]); sp[cof[3]] = (u16)bf16rne(ACC[3]);        \
    }                                                                              \
    float bm_ = fmaxf(fmaxf(ACC[0], ACC[1]), fmaxf(ACC[2], ACC[3]));               \
    bm_ = fmaxf(bm_, __shfl_xor(bm_, 16, 64));                                     \
    bm_ = fmaxf(bm_, __shfl_xor(bm_, 32, 64));                                     \
    if (q == 0) bml[w][m][T] = (u16)bf16rne(bm_); }

  LOADB(bcA, 0)
  for (int t = 0; t < 32; t += 2) {
    LOADB(bcB, t + 1)
    { f32x4 acc; GEMM16(acc, bcA) STORE4(acc, t) }
    if (t + 2 < 32) LOADB(bcA, t + 2)
    { f32x4 acc; GEMM16(acc, bcB) STORE4(acc, t + 1) }
  }
#undef LOADB
#undef GEMM16
#undef STORE4

  // cooperative coalesced bmax write: 64 rows x 32 u16 = one contiguous 4 KB region
  __syncthreads();
  {
    const int row2 = tid >> 2;          // 0..63 (row within the 64-row block)
    const int seg  = tid & 3;           // 4 x 8-u16 segments
    const int wsrc = row2 >> 4, msrc = row2 & 15;
    uint4 v = *(const uint4*)&bml[wsrc][msrc][seg * 8];
    *(uint4*)(bmaxg + ((long long)split * 16384 + rowblk * 64 + row2) * 32 + seg * 8) = v;
  }
}

// ---------------- k_topk_exact: block-max threshold + sparse gather + fp64 rescore ----------------
// R20: threshold from 8th-largest lane-max of the 128 BLOCK-maxes (m8' <= b8 <= v8 =>
//      survivor superset; exact fp64 rescore unchanged). Reads 256 B of bmax + ~15
//      surviving 32 B score blocks per row instead of the full 4 KB score row.
__global__ __launch_bounds__(256) void k_topk_exact(const u16* __restrict__ scores,
                                                    const u16* __restrict__ bmaxg,
                                                    const float* __restrict__ x,
                                                    const double* __restrict__ rinv,
                                                    float* __restrict__ out) {
  __shared__ u32 scnt[4];
  __shared__ u32 sblkn[4];
  __shared__ u32 sblk[4][CAP];
  __shared__ u32 scand[4][CAP];

  const int w = threadIdx.x >> 6, l = threadIdx.x & 63;
  const int r = blockIdx.x * 4 + w;            // 0..16383
  const int n = r & (NN - 1);
  const long long brow = r - n;                // b*NN

  if (l == 0) { scnt[w] = 0u; sblkn[w] = 0u; } // wave-local; LDS in-order, no barrier

  // load the row's 128 block-maxes: lane l -> split s = l>>4, pair idx = l&15
  const int s_ = l >> 4, idx_ = l & 15;
  const u32 bm2 = *(const u32*)(bmaxg + ((long long)s_ * 16384 + r) * 32 + 2 * idx_);
  const float b0 = __uint_as_float(bm2 << 16);
  const float b1 = __uint_as_float(bm2 & 0xFFFF0000u);
  const int blk0 = s_ * 32 + 2 * idx_;         // global 16-col block ids
  float mx = fmaxf(b0, b1);

  // ---- sparse butterfly: top-8 of the 64 lane-maxes (validated R19) ----
  float kv8[8];
  {
    const float o  = __shfl_xor(mx, 1, 64);
    const float h2 = fmaxf(mx, o), l2 = fminf(mx, o);
    const float p0 = __shfl_xor(h2, 2, 64), p1 = __shfl_xor(l2, 2, 64);
    const float m0 = fmaxf(h2, p0);
    const float xx = fminf(h2, p0);
    const float yy = fmaxf(l2, p1);
    const float m3 = fminf(l2, p1);
    const float m1 = fmaxf(xx, yy);
    const float m2 = fminf(xx, yy);
    const float q0 = __shfl_xor(m0, 4, 64), q1 = __shfl_xor(m1, 4, 64);
    const float q2 = __shfl_xor(m2, 4, 64), q3 = __shfl_xor(m3, 4, 64);
    float L[8] = {m0, m1, m2, m3, q3, q2, q1, q0};
    CXF(0, 4) CXF(1, 5) CXF(2, 6) CXF(3, 7)
    CXF(0, 2) CXF(1, 3) CXF(4, 6) CXF(5, 7)
    CXF(0, 1) CXF(2, 3) CXF(4, 5) CXF(6, 7)
    #pragma unroll
    for (int s = 0; s < 8; ++s) kv8[s] = L[s];
    #pragma unroll
    for (int mk = 8; mk <= 32; mk <<= 1) {
      float ov[8];
      #pragma unroll
      for (int s = 0; s < 8; ++s) ov[s] = __shfl_xor(kv8[s], mk, 64);
      merge8f(kv8, ov);
    }
  }
  const float th = kv8[7] - MARGIN;            // m8' - margin <= v8 - margin: superset

  // surviving blocks (>= 8 guaranteed: at least 8 lane-maxes >= m8' > th)
  if (b0 >= th) { const u32 id = atomicAdd(&sblkn[w], 1u); if (id < CAP) sblk[w][id] = (u32)blk0; }
  if (b1 >= th) { const u32 id = atomicAdd(&sblkn[w], 1u); if (id < CAP) sblk[w][id] = (u32)(blk0 + 1); }

  int c;
  const int nbq = (int)sblkn[w];               // wave-lockstep: pushes complete
  const u16* rowp = scores + (long long)r * NN;
  if (nbq <= CAP) {
    // gather surviving blocks' values, 4 blocks per round (16 lanes each)
    for (int i = 0; i < nbq; i += 4) {
      const int bi = i + s_;
      const u32 blk = (bi < nbq) ? sblk[w][bi] : sblk[w][0];
      const int col = (int)blk * 16 + idx_;
      const float v = __uint_as_float((u32)rowp[col] << 16);
      if (bi < nbq && v >= th) {
        const u32 id = atomicAdd(&scnt[w], 1u);
        if (id < CAP) scand[w][id] = (u32)col;
      }
    }
    c = (int)scnt[w];
  } else {
    c = CAP + 1;                               // force exact full-scan fallback
  }

  const float2 a2 = ((const float2*)(x + (long long)r * DD))[l];
  const double ri = rinv[r];
  u64 kv[8];
  #pragma unroll
  for (int s = 0; s < 8; ++s) kv[s] = 0ull;

  if (c <= CAP) {
    for (int i = 0; i < c; i += 4) {
      float2 vv[4]; int col[4];
      #pragma unroll
      for (int g = 0; g < 4; ++g) {
        const int idx = i + g;
        col[g] = (idx < c) ? ((int)scand[w][idx] & (NN - 1)) : 0;
        vv[g] = ((const float2*)(x + (brow + col[g]) * DD))[l];
      }
      #pragma unroll
      for (int g = 0; g < 4; ++g) {
        double d = fma((double)a2.x, (double)vv[g].x, (double)a2.y * (double)vv[g].y);
        #pragma unroll
        for (int mk = 1; mk <= 32; mk <<= 1) d += __shfl_xor(d, mk, 64);
        if (i + g < c) insert8u(kv, make_key(d * ri * rinv[brow + col[g]], col[g]));
      }
    }
  } else {
    // overflow fallback (never expected): full exact row scan (validated)
    for (int base = 0; base < NN; base += 64) {
      const int col = base + l;
      const float* ap = x + (long long)r * DD;
      const float* cp = x + (brow + col) * DD;
      double d = 0.0;
      for (int kk = 0; kk < 64; ++kk) {
        const float2 av = ((const float2*)ap)[kk];
        const float2 bv = ((const float2*)cp)[kk];
        d = fma((double)av.x, (double)bv.x, fma((double)av.y, (double)bv.y, d));
      }
      d = d * ri * rinv[brow + col];
      u64 one[8];
      one[0] = make_key(d, col);
      #pragma unroll
      for (int s = 1; s < 8; ++s) one[s] = 0ull;
      #pragma unroll
      for (int mk = 1; mk <= 32; mk <<= 1) {
        u64 ov[8];
        #pragma unroll
        for (int s = 0; s < 8; ++s) ov[s] = __shfl_xor(one[s], mk, 64);
        merge8(one, ov);
      }
      merge8(kv, one);
    }
  }

  const long long orow = (long long)r * NN;
  const long long obase = brow * NN;           // b*NN*NN
  if (l == 8) out[orow + n] = 1.0f;            // self loop
  #pragma unroll
  for (int s = 0; s < 8; ++s) {
    const int mcol = 2047 - (int)(kv[s] & 2047ull);
    if (l == s) {
      out[orow + mcol] = 1.0f;
      out[obase + (long long)mcol * NN + n] = 1.0f;
    }
  }
}

extern "C" void kernel_launch(void* const* d_in, const int* in_sizes, int n_in,
                              void* d_out, int out_size, void* d_ws, size_t ws_size,
                              hipStream_t stream) {
  const float* x = (const float*)d_in[0];
  float* out = (float*)d_out;
  char* ws = (char*)d_ws;
  u32* nb = (u32*)ws;                                //  4,194,304 B (bf16 normed)
  double* rinv = (double*)(ws + 4194304);            //    131,072 B
  u16* scores = (u16*)(ws + 4325376);                // 67,108,864 B (bf16 scores)
  u16* bmaxg = (u16*)(ws + 71434240);                //  4,194,304 B (16-col block maxes)

  hipLaunchKernelGGL(k_zero, dim3(4096), dim3(256), 0, stream,
                     (float4*)out, out_size / 4);
  hipLaunchKernelGGL(k_normalize, dim3(NROWS / 4), dim3(256), 0, stream, x, rinv, nb);
  hipLaunchKernelGGL(k_gram, dim3(1024), dim3(256), 0, stream, nb, scores, bmaxg);
  hipLaunchKernelGGL(k_topk_exact, dim3(NROWS / 4), dim3(256), 0, stream, scores, bmaxg, x, rinv, out);
}

// Round 4
// 254.261 us; speedup vs baseline: 1.1125x; 1.0648x over previous
//
#include <hip/hip_runtime.h>
#include <cstdint>

#define NN 2048
#define DD 128
#define BATCH 8
#define NROWS 16384
#define MARGIN 0.02f     // rigorous need: 2E + 2*bf16-half-ulp = 0.008 + 0.004 = 0.012
#define CAP 64

typedef __attribute__((ext_vector_type(8))) short bf16x8;
typedef __attribute__((ext_vector_type(4))) float f32x4;
typedef unsigned long long u64;
typedef unsigned int u32;
typedef unsigned short u16;

__device__ __forceinline__ u32 bf16rne(float f) {
  u32 u = __float_as_uint(f);
  return (u + 0x7fffu + ((u >> 16) & 1u)) >> 16;
}

// ---------------- K0: named zero-fill ----------------
__global__ __launch_bounds__(256) void k_zero(float4* __restrict__ out, int n4) {
  int i = blockIdx.x * 256 + threadIdx.x;
  const int stride = gridDim.x * 256;
  const float4 z = {0.0f, 0.0f, 0.0f, 0.0f};
  for (; i < n4; i += stride) out[i] = z;
}

// ---------------- K1: norms + bf16 normalized copy (validated R14-R17) ----------------
__global__ __launch_bounds__(256) void k_normalize(const float* __restrict__ x,
                                                   double* __restrict__ rinv,
                                                   u32* __restrict__ nb) {
  const int wave = threadIdx.x >> 6, lane = threadIdx.x & 63;
  const long long row = (long long)blockIdx.x * 4 + wave;   // 16384 rows
  float2 v = ((const float2*)(x + row * DD))[lane];
  const double d0 = v.x, d1 = v.y;
  double s = d0 * d0 + d1 * d1;
  #pragma unroll
  for (int m = 32; m >= 1; m >>= 1) s += __shfl_xor(s, m, 64);
  double den = sqrt(s); den = den > 1e-12 ? den : 1e-12;
  if (lane == 0) rinv[row] = 1.0 / den;
  double2 o; o.x = d0 / den; o.y = d1 / den;
  nb[row * (DD / 2) + lane] = bf16rne((float)o.x) | (bf16rne((float)o.y) << 16);
}

// ---------------- fp32 top-8 machinery: branch-free merge (validated R12/R18) ----------------
#define CXF(i, j) { const float a_ = L[i], b_ = L[j]; L[i] = fmaxf(a_, b_); L[j] = fminf(a_, b_); }
__device__ __forceinline__ void merge8f(float (&kv)[8], const float (&ov)[8]) {
  float L[8];
  #pragma unroll
  for (int i = 0; i < 8; ++i) L[i] = fmaxf(kv[i], ov[7 - i]);
  CXF(0, 4) CXF(1, 5) CXF(2, 6) CXF(3, 7)
  CXF(0, 2) CXF(1, 3) CXF(4, 6) CXF(5, 7)
  CXF(0, 1) CXF(2, 3) CXF(4, 5) CXF(6, 7)
  #pragma unroll
  for (int i = 0; i < 8; ++i) kv[i] = L[i];
}

// ---------------- u64 exact-key machinery (validated R5-R17) ----------------
__device__ __forceinline__ u64 make_key(double s, int col) {
  u64 u = (u64)__double_as_longlong(s);
  const u64 m = (u64)((long long)u >> 63);
  u ^= (m | 0x8000000000000000ull);
  return (u & ~2047ull) | (u64)(2047 - col);
}
__device__ __forceinline__ u64 umax64(u64 a, u64 b) { return a > b ? a : b; }
__device__ __forceinline__ u64 umin64(u64 a, u64 b) { return a > b ? b : a; }
__device__ __forceinline__ void merge8(u64 (&kv)[8], const u64 (&ov)[8]) {
  u64 L[8];
  #pragma unroll
  for (int i = 0; i < 8; ++i) L[i] = umax64(kv[i], ov[7 - i]);
#define CX(i, j) { const u64 a_ = L[i], b_ = L[j]; L[i] = umax64(a_, b_); L[j] = umin64(a_, b_); }
  CX(0, 4) CX(1, 5) CX(2, 6) CX(3, 7)
  CX(0, 2) CX(1, 3) CX(4, 6) CX(5, 7)
  CX(0, 1) CX(2, 3) CX(4, 5) CX(6, 7)
#undef CX
  #pragma unroll
  for (int i = 0; i < 8; ++i) kv[i] = L[i];
}
__device__ __forceinline__ void insert8u(u64 (&v)[8], u64 nk) {
  if (nk > v[7]) {
    v[7] = nk;
    #pragma unroll
    for (int q = 7; q >= 1; --q) {
      const u64 a = v[q - 1], b = v[q];
      const bool sw = b > a;
      v[q - 1] = sw ? b : a; v[q] = sw ? a : b;
    }
  }
}

// ---------------- k_gram R21: 64-rows-per-wave, 128-col strip per wave ----------------
// Each wave owns 64 A-rows (16 regs) x a PRIVATE 128-col B strip: per 16-col tile,
// 4 B-loads feed 16 MFMAs (was 4 loads : 4 MFMAs with 16 rows/wave). B traffic drops
// 537 MB -> 134 MB (no redundancy), VMEM:MFMA instr ratio 1.25 -> 0.5. Layout probe
// (pr/pr2), STORE semantics, bmax sideband (bf16rne monotone: max/rne commute) kept.
// bmax is now wave-local: bml[w][64 rows][pad 16], each wave writes its own 2 KB
// bmaxg region -- no __syncthreads needed (wave-lockstep LDS, validated pattern).
__global__ __launch_bounds__(256) void k_gram(const u32* __restrict__ nb,
                                              u16* __restrict__ scores,
                                              u16* __restrict__ bmaxg) {
  __shared__ u16 bml[4][64][16];   // [wave][row][t(8)+pad] : 8 KB
  const int tid = threadIdx.x; const int w = tid >> 6; const int l = tid & 63;
  const int q = l >> 4; const int m = l & 15;
  bf16x8 pvals = {0,0,0,0,0,0,0,0}, pones = {0,0,0,0,0,0,0,0};
  if (q == 0) {
    pvals[0] = (short)(__float_as_uint((float)(m + 1)) >> 16);
    pones[0] = (short)(__float_as_uint(1.0f) >> 16);
  }
  const f32x4 z4 = {0.0f, 0.0f, 0.0f, 0.0f};
  const f32x4 pr  = __builtin_amdgcn_mfma_f32_16x16x32_bf16(pvals, pones, z4, 0, 0, 0);
  const f32x4 pr2 = __builtin_amdgcn_mfma_f32_16x16x32_bf16(pones, pvals, z4, 0, 0, 0);
  int cof[4];
  #pragma unroll
  for (int p = 0; p < 4; ++p) cof[p] = (int)pr[p] - 1;
  const int rof = (int)pr2[0] - 1;
  const bool contig = (cof[1] == cof[0] + 1) && (cof[2] == cof[0] + 2) &&
                      (cof[3] == cof[0] + 3) && ((cof[0] & 3) == 0);
  const int rowblk = blockIdx.x >> 2; const int split = blockIdx.x & 3;
  const int row0 = rowblk * 64;
  const int b = rowblk >> 5;
  const int c0w = split * 512 + w * 128;       // this wave's private col strip
  const u32* Bb = nb + ((long long)b * NN + c0w) * (DD / 2);

  // A fragments for all 64 rows: ar4[rf][cc], rows row0 + 16*rf + m
  bf16x8 ar4[4][4];
  #pragma unroll
  for (int rf = 0; rf < 4; ++rf) {
    const u32* Ap = nb + (long long)(row0 + 16 * rf + m) * (DD / 2) + 4 * q;
    #pragma unroll
    for (int cc = 0; cc < 4; ++cc) ar4[rf][cc] = *(const bf16x8*)(Ap + 16 * cc);
  }
  u16* rowb[4];
  #pragma unroll
  for (int rf = 0; rf < 4; ++rf)
    rowb[rf] = scores + (long long)(row0 + 16 * rf + rof) * NN + c0w;

  bf16x8 bcA[4], bcB[4];

#define LOADB(DST, T) { const u32* p_ = Bb + (long long)(16 * (T) + m) * (DD / 2) + 4 * q; \
  _Pragma("unroll") for (int cc = 0; cc < 4; ++cc) DST[cc] = *(const bf16x8*)(p_ + 16 * cc); }
#define STOREB(ACC, T, RF) { u16* sp = rowb[RF] + 16 * (T);                        \
    if (contig) {                                                                  \
      uint2 sv;                                                                    \
      sv.x = bf16rne(ACC[0]) | (bf16rne(ACC[1]) << 16);                            \
      sv.y = bf16rne(ACC[2]) | (bf16rne(ACC[3]) << 16);                            \
      *(uint2*)(sp + cof[0]) = sv;                                                 \
    } else {                                                                       \
      sp[cof[0]] = (u16)bf16rne(ACC[0]); sp[cof[1]] = (u16)bf16rne(ACC[1]);        \
      sp[cof[2]] = (u16)bf16rne(ACC[2]); sp[cof[3]] = (u16)bf16rne(ACC[3]);        \
    }                                                                              \
    float bm_ = fmaxf(fmaxf(ACC[0], ACC[1]), fmaxf(ACC[2], ACC[3]));               \
    bm_ = fmaxf(bm_, __shfl_xor(bm_, 16, 64));                                     \
    bm_ = fmaxf(bm_, __shfl_xor(bm_, 32, 64));                                     \
    if (q == 0) bml[w][16 * (RF) + m][T] = (u16)bf16rne(bm_); }
#define TILE(BC, T) {                                                              \
    _Pragma("unroll") for (int rf = 0; rf < 4; ++rf) {                             \
      f32x4 acc = z4;                                                              \
      _Pragma("unroll") for (int cc = 0; cc < 4; ++cc)                             \
        acc = __builtin_amdgcn_mfma_f32_16x16x32_bf16(BC[cc], ar4[rf][cc], acc, 0, 0, 0); \
      STOREB(acc, T, rf)                                                           \
    } }

  LOADB(bcA, 0)
  #pragma unroll
  for (int t = 0; t < 8; t += 2) {
    LOADB(bcB, t + 1)
    TILE(bcA, t)
    if (t + 2 < 8) LOADB(bcA, t + 2)
    TILE(bcB, t + 1)
  }
#undef LOADB
#undef STOREB
#undef TILE

  // wave-local bmax flush: lane l -> row l, 8 u16 = one uint4 (16 B, aligned)
  {
    const uint4 v = *(const uint4*)&bml[w][l][0];
    *(uint4*)(bmaxg + ((long long)split * 16384 + row0 + l) * 32 + w * 8) = v;
  }
}

// ---------------- k_topk_exact: block-max threshold + sparse gather + fp64 rescore ----------------
// R20 (validated): threshold from 8th-largest lane-max of the 128 BLOCK-maxes (m8' <=
// b8 <= v8 => survivor superset; exact fp64 rescore unchanged). Reads 256 B of bmax +
// ~15 surviving 32 B score blocks per row instead of the full 4 KB score row.
__global__ __launch_bounds__(256) void k_topk_exact(const u16* __restrict__ scores,
                                                    const u16* __restrict__ bmaxg,
                                                    const float* __restrict__ x,
                                                    const double* __restrict__ rinv,
                                                    float* __restrict__ out) {
  __shared__ u32 scnt[4];
  __shared__ u32 sblkn[4];
  __shared__ u32 sblk[4][CAP];
  __shared__ u32 scand[4][CAP];

  const int w = threadIdx.x >> 6, l = threadIdx.x & 63;
  const int r = blockIdx.x * 4 + w;            // 0..16383
  const int n = r & (NN - 1);
  const long long brow = r - n;                // b*NN

  if (l == 0) { scnt[w] = 0u; sblkn[w] = 0u; } // wave-local; LDS in-order, no barrier

  // load the row's 128 block-maxes: lane l -> split s = l>>4, pair idx = l&15
  const int s_ = l >> 4, idx_ = l & 15;
  const u32 bm2 = *(const u32*)(bmaxg + ((long long)s_ * 16384 + r) * 32 + 2 * idx_);
  const float b0 = __uint_as_float(bm2 << 16);
  const float b1 = __uint_as_float(bm2 & 0xFFFF0000u);
  const int blk0 = s_ * 32 + 2 * idx_;         // global 16-col block ids
  float mx = fmaxf(b0, b1);

  // ---- sparse butterfly: top-8 of the 64 lane-maxes (validated R19) ----
  float kv8[8];
  {
    const float o  = __shfl_xor(mx, 1, 64);
    const float h2 = fmaxf(mx, o), l2 = fminf(mx, o);
    const float p0 = __shfl_xor(h2, 2, 64), p1 = __shfl_xor(l2, 2, 64);
    const float m0 = fmaxf(h2, p0);
    const float xx = fminf(h2, p0);
    const float yy = fmaxf(l2, p1);
    const float m3 = fminf(l2, p1);
    const float m1 = fmaxf(xx, yy);
    const float m2 = fminf(xx, yy);
    const float q0 = __shfl_xor(m0, 4, 64), q1 = __shfl_xor(m1, 4, 64);
    const float q2 = __shfl_xor(m2, 4, 64), q3 = __shfl_xor(m3, 4, 64);
    float L[8] = {m0, m1, m2, m3, q3, q2, q1, q0};
    CXF(0, 4) CXF(1, 5) CXF(2, 6) CXF(3, 7)
    CXF(0, 2) CXF(1, 3) CXF(4, 6) CXF(5, 7)
    CXF(0, 1) CXF(2, 3) CXF(4, 5) CXF(6, 7)
    #pragma unroll
    for (int s = 0; s < 8; ++s) kv8[s] = L[s];
    #pragma unroll
    for (int mk = 8; mk <= 32; mk <<= 1) {
      float ov[8];
      #pragma unroll
      for (int s = 0; s < 8; ++s) ov[s] = __shfl_xor(kv8[s], mk, 64);
      merge8f(kv8, ov);
    }
  }
  const float th = kv8[7] - MARGIN;            // m8' - margin <= v8 - margin: superset

  // surviving blocks (>= 8 guaranteed: at least 8 lane-maxes >= m8' > th)
  if (b0 >= th) { const u32 id = atomicAdd(&sblkn[w], 1u); if (id < CAP) sblk[w][id] = (u32)blk0; }
  if (b1 >= th) { const u32 id = atomicAdd(&sblkn[w], 1u); if (id < CAP) sblk[w][id] = (u32)(blk0 + 1); }

  int c;
  const int nbq = (int)sblkn[w];               // wave-lockstep: pushes complete
  const u16* rowp = scores + (long long)r * NN;
  if (nbq <= CAP) {
    // gather surviving blocks' values, 4 blocks per round (16 lanes each)
    for (int i = 0; i < nbq; i += 4) {
      const int bi = i + s_;
      const u32 blk = (bi < nbq) ? sblk[w][bi] : sblk[w][0];
      const int col = (int)blk * 16 + idx_;
      const float v = __uint_as_float((u32)rowp[col] << 16);
      if (bi < nbq && v >= th) {
        const u32 id = atomicAdd(&scnt[w], 1u);
        if (id < CAP) scand[w][id] = (u32)col;
      }
    }
    c = (int)scnt[w];
  } else {
    c = CAP + 1;                               // force exact full-scan fallback
  }

  const float2 a2 = ((const float2*)(x + (long long)r * DD))[l];
  const double ri = rinv[r];
  u64 kv[8];
  #pragma unroll
  for (int s = 0; s < 8; ++s) kv[s] = 0ull;

  if (c <= CAP) {
    for (int i = 0; i < c; i += 4) {
      float2 vv[4]; int col[4];
      #pragma unroll
      for (int g = 0; g < 4; ++g) {
        const int idx = i + g;
        col[g] = (idx < c) ? ((int)scand[w][idx] & (NN - 1)) : 0;
        vv[g] = ((const float2*)(x + (brow + col[g]) * DD))[l];
      }
      #pragma unroll
      for (int g = 0; g < 4; ++g) {
        double d = fma((double)a2.x, (double)vv[g].x, (double)a2.y * (double)vv[g].y);
        #pragma unroll
        for (int mk = 1; mk <= 32; mk <<= 1) d += __shfl_xor(d, mk, 64);
        if (i + g < c) insert8u(kv, make_key(d * ri * rinv[brow + col[g]], col[g]));
      }
    }
  } else {
    // overflow fallback (never expected): full exact row scan (validated)
    for (int base = 0; base < NN; base += 64) {
      const int col = base + l;
      const float* ap = x + (long long)r * DD;
      const float* cp = x + (brow + col) * DD;
      double d = 0.0;
      for (int kk = 0; kk < 64; ++kk) {
        const float2 av = ((const float2*)ap)[kk];
        const float2 bv = ((const float2*)cp)[kk];
        d = fma((double)av.x, (double)bv.x, fma((double)av.y, (double)bv.y, d));
      }
      d = d * ri * rinv[brow + col];
      u64 one[8];
      one[0] = make_key(d, col);
      #pragma unroll
      for (int s = 1; s < 8; ++s) one[s] = 0ull;
      #pragma unroll
      for (int mk = 1; mk <= 32; mk <<= 1) {
        u64 ov[8];
        #pragma unroll
        for (int s = 0; s < 8; ++s) ov[s] = __shfl_xor(one[s], mk, 64);
        merge8(one, ov);
      }
      merge8(kv, one);
    }
  }

  const long long orow = (long long)r * NN;
  const long long obase = brow * NN;           // b*NN*NN
  if (l == 8) out[orow + n] = 1.0f;            // self loop
  #pragma unroll
  for (int s = 0; s < 8; ++s) {
    const int mcol = 2047 - (int)(kv[s] & 2047ull);
    if (l == s) {
      out[orow + mcol] = 1.0f;
      out[obase + (long long)mcol * NN + n] = 1.0f;
    }
  }
}

extern "C" void kernel_launch(void* const* d_in, const int* in_sizes, int n_in,
                              void* d_out, int out_size, void* d_ws, size_t ws_size,
                              hipStream_t stream) {
  const float* x = (const float*)d_in[0];
  float* out = (float*)d_out;
  char* ws = (char*)d_ws;
  u32* nb = (u32*)ws;                                //  4,194,304 B (bf16 normed)
  double* rinv = (double*)(ws + 4194304);            //    131,072 B
  u16* scores = (u16*)(ws + 4325376);                // 67,108,864 B (bf16 scores)
  u16* bmaxg = (u16*)(ws + 71434240);                //  4,194,304 B (16-col block maxes)

  hipLaunchKernelGGL(k_zero, dim3(4096), dim3(256), 0, stream,
                     (float4*)out, out_size / 4);
  hipLaunchKernelGGL(k_normalize, dim3(NROWS / 4), dim3(256), 0, stream, x, rinv, nb);
  hipLaunchKernelGGL(k_gram, dim3(1024), dim3(256), 0, stream, nb, scores, bmaxg);
  hipLaunchKernelGGL(k_topk_exact, dim3(NROWS / 4), dim3(256), 0, stream, scores, bmaxg, x, rinv, out);
}

// Round 6
// 248.119 us; speedup vs baseline: 1.1400x; 1.0248x over previous
//
#include <hip/hip_runtime.h>
#include <cstdint>

#define NN 2048
#define DD 128
#define BATCH 8
#define NROWS 16384
#define MARGIN 0.02f     // rigorous need: 2E + 2*bf16-half-ulp = 0.008 + 0.004 = 0.012
#define CAP 64

typedef __attribute__((ext_vector_type(8))) short bf16x8;
typedef __attribute__((ext_vector_type(4))) float f32x4;
typedef unsigned long long u64;
typedef unsigned int u32;
typedef unsigned short u16;

__device__ __forceinline__ u32 bf16rne(float f) {
  u32 u = __float_as_uint(f);
  return (u + 0x7fffu + ((u >> 16) & 1u)) >> 16;
}

// ---------------- K1: norms + bf16 normalized copy (validated R14-R17) ----------------
__global__ __launch_bounds__(256) void k_normalize(const float* __restrict__ x,
                                                   double* __restrict__ rinv,
                                                   u32* __restrict__ nb) {
  const int wave = threadIdx.x >> 6, lane = threadIdx.x & 63;
  const long long row = (long long)blockIdx.x * 4 + wave;   // 16384 rows
  float2 v = ((const float2*)(x + row * DD))[lane];
  const double d0 = v.x, d1 = v.y;
  double s = d0 * d0 + d1 * d1;
  #pragma unroll
  for (int m = 32; m >= 1; m >>= 1) s += __shfl_xor(s, m, 64);
  double den = sqrt(s); den = den > 1e-12 ? den : 1e-12;
  if (lane == 0) rinv[row] = 1.0 / den;
  double2 o; o.x = d0 / den; o.y = d1 / den;
  nb[row * (DD / 2) + lane] = bf16rne((float)o.x) | (bf16rne((float)o.y) << 16);
}

// ---------------- fp32 top-8 machinery: branch-free merge (validated R12/R18) ----------------
#define CXF(i, j) { const float a_ = L[i], b_ = L[j]; L[i] = fmaxf(a_, b_); L[j] = fminf(a_, b_); }
__device__ __forceinline__ void merge8f(float (&kv)[8], const float (&ov)[8]) {
  float L[8];
  #pragma unroll
  for (int i = 0; i < 8; ++i) L[i] = fmaxf(kv[i], ov[7 - i]);
  CXF(0, 4) CXF(1, 5) CXF(2, 6) CXF(3, 7)
  CXF(0, 2) CXF(1, 3) CXF(4, 6) CXF(5, 7)
  CXF(0, 1) CXF(2, 3) CXF(4, 5) CXF(6, 7)
  #pragma unroll
  for (int i = 0; i < 8; ++i) kv[i] = L[i];
}

// ---------------- u64 exact-key machinery (validated R5-R17) ----------------
__device__ __forceinline__ u64 make_key(double s, int col) {
  u64 u = (u64)__double_as_longlong(s);
  const u64 m = (u64)((long long)u >> 63);
  u ^= (m | 0x8000000000000000ull);
  return (u & ~2047ull) | (u64)(2047 - col);
}
__device__ __forceinline__ u64 umax64(u64 a, u64 b) { return a > b ? a : b; }
__device__ __forceinline__ u64 umin64(u64 a, u64 b) { return a > b ? b : a; }
__device__ __forceinline__ void merge8(u64 (&kv)[8], const u64 (&ov)[8]) {
  u64 L[8];
  #pragma unroll
  for (int i = 0; i < 8; ++i) L[i] = umax64(kv[i], ov[7 - i]);
#define CX(i, j) { const u64 a_ = L[i], b_ = L[j]; L[i] = umax64(a_, b_); L[j] = umin64(a_, b_); }
  CX(0, 4) CX(1, 5) CX(2, 6) CX(3, 7)
  CX(0, 2) CX(1, 3) CX(4, 6) CX(5, 7)
  CX(0, 1) CX(2, 3) CX(4, 5) CX(6, 7)
#undef CX
  #pragma unroll
  for (int i = 0; i < 8; ++i) kv[i] = L[i];
}
__device__ __forceinline__ void insert8u(u64 (&v)[8], u64 nk) {
  if (nk > v[7]) {
    v[7] = nk;
    #pragma unroll
    for (int q = 7; q >= 1; --q) {
      const u64 a = v[q - 1], b = v[q];
      const bool sw = b > a;
      v[q - 1] = sw ? b : a; v[q] = sw ? a : b;
    }
  }
}

// ---------------- k_gram R23: R21 structure + output-zero tail (size FIXED) ----------------
// R21 (validated): 64 rows/wave x private 128-col strip; 4 B-loads : 16 MFMAs.
// R23: fold the 134 MB output zeroing into gram's tail. out = 33,554,432 floats
// = 8,388,608 float4 = 262,144 threads x 32 float4 (R22 had 128 -> 4x overrun,
// memory fault). Stores drain while laggard waves still compute.
__global__ __launch_bounds__(256) void k_gram(const u32* __restrict__ nb,
                                              u16* __restrict__ scores,
                                              u16* __restrict__ bmaxg,
                                              float4* __restrict__ outz) {
  __shared__ u16 bml[4][64][16];   // [wave][row][t(8)+pad] : 8 KB
  const int tid = threadIdx.x; const int w = tid >> 6; const int l = tid & 63;
  const int q = l >> 4; const int m = l & 15;
  bf16x8 pvals = {0,0,0,0,0,0,0,0}, pones = {0,0,0,0,0,0,0,0};
  if (q == 0) {
    pvals[0] = (short)(__float_as_uint((float)(m + 1)) >> 16);
    pones[0] = (short)(__float_as_uint(1.0f) >> 16);
  }
  const f32x4 z4 = {0.0f, 0.0f, 0.0f, 0.0f};
  const f32x4 pr  = __builtin_amdgcn_mfma_f32_16x16x32_bf16(pvals, pones, z4, 0, 0, 0);
  const f32x4 pr2 = __builtin_amdgcn_mfma_f32_16x16x32_bf16(pones, pvals, z4, 0, 0, 0);
  int cof[4];
  #pragma unroll
  for (int p = 0; p < 4; ++p) cof[p] = (int)pr[p] - 1;
  const int rof = (int)pr2[0] - 1;
  const bool contig = (cof[1] == cof[0] + 1) && (cof[2] == cof[0] + 2) &&
                      (cof[3] == cof[0] + 3) && ((cof[0] & 3) == 0);
  const int rowblk = blockIdx.x >> 2; const int split = blockIdx.x & 3;
  const int row0 = rowblk * 64;
  const int b = rowblk >> 5;
  const int c0w = split * 512 + w * 128;       // this wave's private col strip
  const u32* Bb = nb + ((long long)b * NN + c0w) * (DD / 2);

  // A fragments for all 64 rows: ar4[rf][cc], rows row0 + 16*rf + m
  bf16x8 ar4[4][4];
  #pragma unroll
  for (int rf = 0; rf < 4; ++rf) {
    const u32* Ap = nb + (long long)(row0 + 16 * rf + m) * (DD / 2) + 4 * q;
    #pragma unroll
    for (int cc = 0; cc < 4; ++cc) ar4[rf][cc] = *(const bf16x8*)(Ap + 16 * cc);
  }
  u16* rowb[4];
  #pragma unroll
  for (int rf = 0; rf < 4; ++rf)
    rowb[rf] = scores + (long long)(row0 + 16 * rf + rof) * NN + c0w;

  bf16x8 bcA[4], bcB[4];

#define LOADB(DST, T) { const u32* p_ = Bb + (long long)(16 * (T) + m) * (DD / 2) + 4 * q; \
  _Pragma("unroll") for (int cc = 0; cc < 4; ++cc) DST[cc] = *(const bf16x8*)(p_ + 16 * cc); }
#define STOREB(ACC, T, RF) { u16* sp = rowb[RF] + 16 * (T);                        \
    if (contig) {                                                                  \
      uint2 sv;                                                                    \
      sv.x = bf16rne(ACC[0]) | (bf16rne(ACC[1]) << 16);                            \
      sv.y = bf16rne(ACC[2]) | (bf16rne(ACC[3]) << 16);                            \
      *(uint2*)(sp + cof[0]) = sv;                                                 \
    } else {                                                                       \
      sp[cof[0]] = (u16)bf16rne(ACC[0]); sp[cof[1]] = (u16)bf16rne(ACC[1]);        \
      sp[cof[2]] = (u16)bf16rne(ACC[2]); sp[cof[3]] = (u16)bf16rne(ACC[3]);        \
    }                                                                              \
    float bm_ = fmaxf(fmaxf(ACC[0], ACC[1]), fmaxf(ACC[2], ACC[3]));               \
    bm_ = fmaxf(bm_, __shfl_xor(bm_, 16, 64));                                     \
    bm_ = fmaxf(bm_, __shfl_xor(bm_, 32, 64));                                     \
    if (q == 0) bml[w][16 * (RF) + m][T] = (u16)bf16rne(bm_); }
#define TILE(BC, T) {                                                              \
    _Pragma("unroll") for (int rf = 0; rf < 4; ++rf) {                             \
      f32x4 acc = z4;                                                              \
      _Pragma("unroll") for (int cc = 0; cc < 4; ++cc)                             \
        acc = __builtin_amdgcn_mfma_f32_16x16x32_bf16(BC[cc], ar4[rf][cc], acc, 0, 0, 0); \
      STOREB(acc, T, rf)                                                           \
    } }

  LOADB(bcA, 0)
  #pragma unroll
  for (int t = 0; t < 8; t += 2) {
    LOADB(bcB, t + 1)
    TILE(bcA, t)
    if (t + 2 < 8) LOADB(bcA, t + 2)
    TILE(bcB, t + 1)
  }
#undef LOADB
#undef STOREB
#undef TILE

  // wave-local bmax flush: lane l -> row l, 8 u16 = one uint4 (16 B, aligned)
  {
    const uint4 v = *(const uint4*)&bml[w][l][0];
    *(uint4*)(bmaxg + ((long long)split * 16384 + row0 + l) * 32 + w * 8) = v;
  }

  // R23: output zero tail. 262,144 threads x 32 float4 = 8,388,608 float4 = 134 MB.
  {
    const int base = blockIdx.x * 256 + tid;
    const float4 zf = {0.0f, 0.0f, 0.0f, 0.0f};
    #pragma unroll 8
    for (int k = 0; k < 32; ++k) outz[base + k * 262144] = zf;
  }
}

// ---------------- k_topk_exact: block-max threshold + sparse gather + fp64 rescore ----------------
// R20 (validated): threshold from 8th-largest lane-max of the 128 BLOCK-maxes (m8' <=
// b8 <= v8 => survivor superset; exact fp64 rescore unchanged).
// R23: 16-lane-GROUP rescore -- 4 survivors in parallel. Each group's lane covers 8
// dims (8 fp64 FMA), butterfly xor 1..8 only (4 steps, in-group), per-group top-8
// insert (group-uniform branch), then 2 cross-group u64 merges. Cuts bpermute count
// ~2x and serial butterfly depth ~5x vs one-survivor-per-wave.
__global__ __launch_bounds__(256) void k_topk_exact(const u16* __restrict__ scores,
                                                    const u16* __restrict__ bmaxg,
                                                    const float* __restrict__ x,
                                                    const double* __restrict__ rinv,
                                                    float* __restrict__ out) {
  __shared__ u32 scnt[4];
  __shared__ u32 sblkn[4];
  __shared__ u32 sblk[4][CAP];
  __shared__ u32 scand[4][CAP];

  const int w = threadIdx.x >> 6, l = threadIdx.x & 63;
  const int r = blockIdx.x * 4 + w;            // 0..16383
  const int n = r & (NN - 1);
  const long long brow = r - n;                // b*NN

  if (l == 0) { scnt[w] = 0u; sblkn[w] = 0u; } // wave-local; LDS in-order, no barrier

  // load the row's 128 block-maxes: lane l -> split s = l>>4, pair idx = l&15
  const int s_ = l >> 4, idx_ = l & 15;
  const u32 bm2 = *(const u32*)(bmaxg + ((long long)s_ * 16384 + r) * 32 + 2 * idx_);
  const float b0 = __uint_as_float(bm2 << 16);
  const float b1 = __uint_as_float(bm2 & 0xFFFF0000u);
  const int blk0 = s_ * 32 + 2 * idx_;         // global 16-col block ids
  float mx = fmaxf(b0, b1);

  // ---- sparse butterfly: top-8 of the 64 lane-maxes (validated R19) ----
  float kv8[8];
  {
    const float o  = __shfl_xor(mx, 1, 64);
    const float h2 = fmaxf(mx, o), l2 = fminf(mx, o);
    const float p0 = __shfl_xor(h2, 2, 64), p1 = __shfl_xor(l2, 2, 64);
    const float m0 = fmaxf(h2, p0);
    const float xx = fminf(h2, p0);
    const float yy = fmaxf(l2, p1);
    const float m3 = fminf(l2, p1);
    const float m1 = fmaxf(xx, yy);
    const float m2 = fminf(xx, yy);
    const float q0 = __shfl_xor(m0, 4, 64), q1 = __shfl_xor(m1, 4, 64);
    const float q2 = __shfl_xor(m2, 4, 64), q3 = __shfl_xor(m3, 4, 64);
    float L[8] = {m0, m1, m2, m3, q3, q2, q1, q0};
    CXF(0, 4) CXF(1, 5) CXF(2, 6) CXF(3, 7)
    CXF(0, 2) CXF(1, 3) CXF(4, 6) CXF(5, 7)
    CXF(0, 1) CXF(2, 3) CXF(4, 5) CXF(6, 7)
    #pragma unroll
    for (int s = 0; s < 8; ++s) kv8[s] = L[s];
    #pragma unroll
    for (int mk = 8; mk <= 32; mk <<= 1) {
      float ov[8];
      #pragma unroll
      for (int s = 0; s < 8; ++s) ov[s] = __shfl_xor(kv8[s], mk, 64);
      merge8f(kv8, ov);
    }
  }
  const float th = kv8[7] - MARGIN;            // m8' - margin <= v8 - margin: superset

  // surviving blocks (>= 8 guaranteed: at least 8 lane-maxes >= m8' > th)
  if (b0 >= th) { const u32 id = atomicAdd(&sblkn[w], 1u); if (id < CAP) sblk[w][id] = (u32)blk0; }
  if (b1 >= th) { const u32 id = atomicAdd(&sblkn[w], 1u); if (id < CAP) sblk[w][id] = (u32)(blk0 + 1); }

  int c;
  const int nbq = (int)sblkn[w];               // wave-lockstep: pushes complete
  const u16* rowp = scores + (long long)r * NN;
  if (nbq <= CAP) {
    // gather surviving blocks' values, 4 blocks per round (16 lanes each)
    for (int i = 0; i < nbq; i += 4) {
      const int bi = i + s_;
      const u32 blk = (bi < nbq) ? sblk[w][bi] : sblk[w][0];
      const int col = (int)blk * 16 + idx_;
      const float v = __uint_as_float((u32)rowp[col] << 16);
      if (bi < nbq && v >= th) {
        const u32 id = atomicAdd(&scnt[w], 1u);
        if (id < CAP) scand[w][id] = (u32)col;
      }
    }
    c = (int)scnt[w];
  } else {
    c = CAP + 1;                               // force exact full-scan fallback
  }

  const double ri = rinv[r];
  u64 kv[8];
  #pragma unroll
  for (int s = 0; s < 8; ++s) kv[s] = 0ull;

  if (c <= CAP) {
    // own-row values at group positions: lane covers dims of float2 idx_ + 16j
    float2 a4[4];
    #pragma unroll
    for (int j = 0; j < 4; ++j)
      a4[j] = ((const float2*)(x + (long long)r * DD))[idx_ + 16 * j];

    for (int i = 0; i < c; i += 4) {
      const int gi = i + s_;
      const bool valid = gi < c;
      const int col = valid ? ((int)scand[w][gi] & (NN - 1)) : 0;
      const float2* cp = (const float2*)(x + (brow + col) * DD);
      double d = 0.0;
      #pragma unroll
      for (int j = 0; j < 4; ++j) {
        const float2 bv = cp[idx_ + 16 * j];
        d = fma((double)a4[j].x, (double)bv.x, d);
        d = fma((double)a4[j].y, (double)bv.y, d);
      }
      #pragma unroll
      for (int mk = 1; mk <= 8; mk <<= 1) d += __shfl_xor(d, mk, 64);
      if (valid) insert8u(kv, make_key(d * ri * rinv[brow + col], col));
    }
    // cross-group merges: all 64 lanes converge to the row's top-8
    #pragma unroll
    for (int mk = 16; mk <= 32; mk <<= 1) {
      u64 ov[8];
      #pragma unroll
      for (int s = 0; s < 8; ++s) ov[s] = __shfl_xor(kv[s], mk, 64);
      merge8(kv, ov);
    }
  } else {
    // overflow fallback (never expected): full exact row scan (validated)
    for (int base = 0; base < NN; base += 64) {
      const int col = base + l;
      const float* ap = x + (long long)r * DD;
      const float* cp = x + (brow + col) * DD;
      double d = 0.0;
      for (int kk = 0; kk < 64; ++kk) {
        const float2 av = ((const float2*)ap)[kk];
        const float2 bv = ((const float2*)cp)[kk];
        d = fma((double)av.x, (double)bv.x, fma((double)av.y, (double)bv.y, d));
      }
      d = d * ri * rinv[brow + col];
      u64 one[8];
      one[0] = make_key(d, col);
      #pragma unroll
      for (int s = 1; s < 8; ++s) one[s] = 0ull;
      #pragma unroll
      for (int mk = 1; mk <= 32; mk <<= 1) {
        u64 ov[8];
        #pragma unroll
        for (int s = 0; s < 8; ++s) ov[s] = __shfl_xor(one[s], mk, 64);
        merge8(one, ov);
      }
      merge8(kv, one);
    }
  }

  const long long orow = (long long)r * NN;
  const long long obase = brow * NN;           // b*NN*NN
  if (l == 8) out[orow + n] = 1.0f;            // self loop
  #pragma unroll
  for (int s = 0; s < 8; ++s) {
    const int mcol = 2047 - (int)(kv[s] & 2047ull);
    if (l == s) {
      out[orow + mcol] = 1.0f;
      out[obase + (long long)mcol * NN + n] = 1.0f;
    }
  }
}

extern "C" void kernel_launch(void* const* d_in, const int* in_sizes, int n_in,
                              void* d_out, int out_size, void* d_ws, size_t ws_size,
                              hipStream_t stream) {
  const float* x = (const float*)d_in[0];
  float* out = (float*)d_out;
  char* ws = (char*)d_ws;
  u32* nb = (u32*)ws;                                //  4,194,304 B (bf16 normed)
  double* rinv = (double*)(ws + 4194304);            //    131,072 B
  u16* scores = (u16*)(ws + 4325376);                // 67,108,864 B (bf16 scores)
  u16* bmaxg = (u16*)(ws + 71434240);                //  4,194,304 B (16-col block maxes)

  hipLaunchKernelGGL(k_normalize, dim3(NROWS / 4), dim3(256), 0, stream, x, rinv, nb);
  hipLaunchKernelGGL(k_gram, dim3(1024), dim3(256), 0, stream, nb, scores, bmaxg,
                     (float4*)out);
  hipLaunchKernelGGL(k_topk_exact, dim3(NROWS / 4), dim3(256), 0, stream, scores, bmaxg, x, rinv, out);
}

// Round 7
// 243.696 us; speedup vs baseline: 1.1607x; 1.0181x over previous
//
#include <hip/hip_runtime.h>
#include <cstdint>

#define NN 2048
#define DD 128
#define BATCH 8
#define NROWS 16384
#define MARGIN 0.02f     // need: 2E + bmax-round-up + filter slack = ~0.012; 0.02 holds
#define CAP2 48

typedef __attribute__((ext_vector_type(8))) short bf16x8;
typedef __attribute__((ext_vector_type(4))) float f32x4;
typedef unsigned long long u64;
typedef unsigned int u32;
typedef unsigned short u16;

__device__ __forceinline__ u32 bf16rne(float f) {
  u32 u = __float_as_uint(f);
  return (u + 0x7fffu + ((u >> 16) & 1u)) >> 16;
}

// ---------------- K1: norms + bf16 normalized copy (validated R14-R17) ----------------
__global__ __launch_bounds__(256) void k_normalize(const float* __restrict__ x,
                                                   double* __restrict__ rinv,
                                                   u32* __restrict__ nb) {
  const int wave = threadIdx.x >> 6, lane = threadIdx.x & 63;
  const long long row = (long long)blockIdx.x * 4 + wave;   // 16384 rows
  float2 v = ((const float2*)(x + row * DD))[lane];
  const double d0 = v.x, d1 = v.y;
  double s = d0 * d0 + d1 * d1;
  #pragma unroll
  for (int m = 32; m >= 1; m >>= 1) s += __shfl_xor(s, m, 64);
  double den = sqrt(s); den = den > 1e-12 ? den : 1e-12;
  if (lane == 0) rinv[row] = 1.0 / den;
  double2 o; o.x = d0 / den; o.y = d1 / den;
  nb[row * (DD / 2) + lane] = bf16rne((float)o.x) | (bf16rne((float)o.y) << 16);
}

// ---------------- fp32 top-8 machinery: branch-free merge (validated R12/R18) ----------------
#define CXF(i, j) { const float a_ = L[i], b_ = L[j]; L[i] = fmaxf(a_, b_); L[j] = fminf(a_, b_); }
__device__ __forceinline__ void merge8f(float (&kv)[8], const float (&ov)[8]) {
  float L[8];
  #pragma unroll
  for (int i = 0; i < 8; ++i) L[i] = fmaxf(kv[i], ov[7 - i]);
  CXF(0, 4) CXF(1, 5) CXF(2, 6) CXF(3, 7)
  CXF(0, 2) CXF(1, 3) CXF(4, 6) CXF(5, 7)
  CXF(0, 1) CXF(2, 3) CXF(4, 5) CXF(6, 7)
  #pragma unroll
  for (int i = 0; i < 8; ++i) kv[i] = L[i];
}

// ---------------- u64 exact-key machinery (validated R5-R17) ----------------
__device__ __forceinline__ u64 make_key(double s, int col) {
  u64 u = (u64)__double_as_longlong(s);
  const u64 m = (u64)((long long)u >> 63);
  u ^= (m | 0x8000000000000000ull);
  return (u & ~2047ull) | (u64)(2047 - col);
}
__device__ __forceinline__ u64 umax64(u64 a, u64 b) { return a > b ? a : b; }
__device__ __forceinline__ u64 umin64(u64 a, u64 b) { return a > b ? b : a; }
__device__ __forceinline__ void merge8(u64 (&kv)[8], const u64 (&ov)[8]) {
  u64 L[8];
  #pragma unroll
  for (int i = 0; i < 8; ++i) L[i] = umax64(kv[i], ov[7 - i]);
#define CX(i, j) { const u64 a_ = L[i], b_ = L[j]; L[i] = umax64(a_, b_); L[j] = umin64(a_, b_); }
  CX(0, 4) CX(1, 5) CX(2, 6) CX(3, 7)
  CX(0, 2) CX(1, 3) CX(4, 6) CX(5, 7)
  CX(0, 1) CX(2, 3) CX(4, 5) CX(6, 7)
#undef CX
  #pragma unroll
  for (int i = 0; i < 8; ++i) kv[i] = L[i];
}
__device__ __forceinline__ void insert8u(u64 (&v)[8], u64 nk) {
  if (nk > v[7]) {
    v[7] = nk;
    #pragma unroll
    for (int q = 7; q >= 1; --q) {
      const u64 a = v[q - 1], b = v[q];
      const bool sw = b > a;
      v[q - 1] = sw ? b : a; v[q] = sw ? a : b;
    }
  }
}

// ---------------- k_gram_bmax R24: bmax-only gram (NO score materialization) ----------------
// R21 structure (64 rows/wave x private 128-col strip), score stores DELETED. Writes
// only the 4 MB block-max sideband + the 134 MB output zero tail. K2 recomputes
// scores bit-identically (same MFMA, same inputs) for surviving blocks.
__global__ __launch_bounds__(256) void k_gram_bmax(const u32* __restrict__ nb,
                                                   u16* __restrict__ bmaxg,
                                                   float4* __restrict__ outz) {
  __shared__ u16 bml[4][64][16];   // [wave][row][t(8)+pad] : 8 KB
  const int tid = threadIdx.x; const int w = tid >> 6; const int l = tid & 63;
  const int q = l >> 4; const int m = l & 15;
  const f32x4 z4 = {0.0f, 0.0f, 0.0f, 0.0f};
  const int rowblk = blockIdx.x >> 2; const int split = blockIdx.x & 3;
  const int row0 = rowblk * 64;
  const int b = rowblk >> 5;
  const int c0w = split * 512 + w * 128;       // this wave's private col strip
  const u32* Bb = nb + ((long long)b * NN + c0w) * (DD / 2);

  bf16x8 ar4[4][4];
  #pragma unroll
  for (int rf = 0; rf < 4; ++rf) {
    const u32* Ap = nb + (long long)(row0 + 16 * rf + m) * (DD / 2) + 4 * q;
    #pragma unroll
    for (int cc = 0; cc < 4; ++cc) ar4[rf][cc] = *(const bf16x8*)(Ap + 16 * cc);
  }
  bf16x8 bcA[4], bcB[4];

#define LOADB(DST, T) { const u32* p_ = Bb + (long long)(16 * (T) + m) * (DD / 2) + 4 * q; \
  _Pragma("unroll") for (int cc = 0; cc < 4; ++cc) DST[cc] = *(const bf16x8*)(p_ + 16 * cc); }
#define TILE1(BC, T) {                                                             \
    _Pragma("unroll") for (int rf = 0; rf < 4; ++rf) {                             \
      f32x4 acc = z4;                                                              \
      _Pragma("unroll") for (int cc = 0; cc < 4; ++cc)                             \
        acc = __builtin_amdgcn_mfma_f32_16x16x32_bf16(BC[cc], ar4[rf][cc], acc, 0, 0, 0); \
      float bm_ = fmaxf(fmaxf(acc[0], acc[1]), fmaxf(acc[2], acc[3]));             \
      bm_ = fmaxf(bm_, __shfl_xor(bm_, 16, 64));                                   \
      bm_ = fmaxf(bm_, __shfl_xor(bm_, 32, 64));                                   \
      if (q == 0) bml[w][16 * rf + m][T] = (u16)bf16rne(bm_);                      \
    } }

  LOADB(bcA, 0)
  #pragma unroll
  for (int t = 0; t < 8; t += 2) {
    LOADB(bcB, t + 1)
    TILE1(bcA, t)
    if (t + 2 < 8) LOADB(bcA, t + 2)
    TILE1(bcB, t + 1)
  }
#undef LOADB
#undef TILE1

  // wave-local bmax flush: lane l -> row l, 8 u16 = one uint4 (validated R23)
  {
    const uint4 v = *(const uint4*)&bml[w][l][0];
    *(uint4*)(bmaxg + ((long long)split * 16384 + row0 + l) * 32 + w * 8) = v;
  }

  // output zero tail: 262,144 threads x 32 float4 = 8,388,608 float4 = 134 MB (validated R23)
  {
    const int base = blockIdx.x * 256 + tid;
    const float4 zf = {0.0f, 0.0f, 0.0f, 0.0f};
    #pragma unroll 8
    for (int k = 0; k < 32; ++k) outz[base + k * 262144] = zf;
  }
}

// ---------------- k_topk_fused R24: threshold + MFMA recompute + filter + fp64 rescore ----------------
// One workgroup = 64 rows x all 2048 cols (8 waves x 256-col strips).
// Phase A: per-row thresholds from bmax (validated R19/R20 butterfly; m8' - MARGIN).
// Phase B: recompute all tiles by MFMA (bit-identical to K1's fp32 values), filter
//          v >= th in-register, push surviving cols to per-row LDS lists (~16/row).
// Phase C: validated 16-lane-group fp64 rescore (R23) per row + output writes.
__global__ __launch_bounds__(512) void k_topk_fused(const u32* __restrict__ nb,
                                                    const u16* __restrict__ bmaxg,
                                                    const float* __restrict__ x,
                                                    const double* __restrict__ rinv,
                                                    float* __restrict__ out) {
  __shared__ float thl[64];
  __shared__ u32 cnt[64];
  __shared__ u32 cand[64][CAP2];

  const int tid = threadIdx.x; const int w = tid >> 6; const int l = tid & 63;
  const int q = l >> 4; const int m = l & 15;
  const int s_ = q, idx_ = m;
  const int rowblk = blockIdx.x;               // 0..255
  const int row0 = rowblk * 64;
  const int b = rowblk >> 5;
  const long long brow = (long long)b * NN;

  // ---- runtime MFMA layout probe (validated R17) ----
  bf16x8 pvals = {0,0,0,0,0,0,0,0}, pones = {0,0,0,0,0,0,0,0};
  if (q == 0) {
    pvals[0] = (short)(__float_as_uint((float)(m + 1)) >> 16);
    pones[0] = (short)(__float_as_uint(1.0f) >> 16);
  }
  const f32x4 z4 = {0.0f, 0.0f, 0.0f, 0.0f};
  const f32x4 pr  = __builtin_amdgcn_mfma_f32_16x16x32_bf16(pvals, pones, z4, 0, 0, 0);
  const f32x4 pr2 = __builtin_amdgcn_mfma_f32_16x16x32_bf16(pones, pvals, z4, 0, 0, 0);
  int cof[4];
  #pragma unroll
  for (int p = 0; p < 4; ++p) cof[p] = (int)pr[p] - 1;
  const int rof = (int)pr2[0] - 1;

  if (tid < 64) cnt[tid] = 0u;

  // ---- Phase A: thresholds for this wave's 8 rows (validated butterfly) ----
  for (int j = 0; j < 8; ++j) {
    const int rib = w * 8 + j;
    const int row = row0 + rib;
    const u32 bm2 = *(const u32*)(bmaxg + ((long long)s_ * 16384 + row) * 32 + 2 * idx_);
    const float b0 = __uint_as_float(bm2 << 16);
    const float b1 = __uint_as_float(bm2 & 0xFFFF0000u);
    float mx = fmaxf(b0, b1);
    float kv8[8];
    {
      const float o  = __shfl_xor(mx, 1, 64);
      const float h2 = fmaxf(mx, o), l2 = fminf(mx, o);
      const float p0 = __shfl_xor(h2, 2, 64), p1 = __shfl_xor(l2, 2, 64);
      const float m0 = fmaxf(h2, p0);
      const float xx = fminf(h2, p0);
      const float yy = fmaxf(l2, p1);
      const float m3 = fminf(l2, p1);
      const float m1 = fmaxf(xx, yy);
      const float m2 = fminf(xx, yy);
      const float q0 = __shfl_xor(m0, 4, 64), q1 = __shfl_xor(m1, 4, 64);
      const float q2 = __shfl_xor(m2, 4, 64), q3 = __shfl_xor(m3, 4, 64);
      float L[8] = {m0, m1, m2, m3, q3, q2, q1, q0};
      CXF(0, 4) CXF(1, 5) CXF(2, 6) CXF(3, 7)
      CXF(0, 2) CXF(1, 3) CXF(4, 6) CXF(5, 7)
      CXF(0, 1) CXF(2, 3) CXF(4, 5) CXF(6, 7)
      #pragma unroll
      for (int s = 0; s < 8; ++s) kv8[s] = L[s];
      #pragma unroll
      for (int mk = 8; mk <= 32; mk <<= 1) {
        float ov[8];
        #pragma unroll
        for (int s = 0; s < 8; ++s) ov[s] = __shfl_xor(kv8[s], mk, 64);
        merge8f(kv8, ov);
      }
    }
    if (l == 0) thl[rib] = kv8[7] - MARGIN;
  }
  __syncthreads();

  // per-lane row bindings + thresholds for the filter
  float th4[4]; int rib4[4];
  #pragma unroll
  for (int rf = 0; rf < 4; ++rf) {
    rib4[rf] = 16 * rf + rof;
    th4[rf] = thl[rib4[rf]];
  }

  // ---- Phase B: MFMA recompute + filter + push ----
  const int c0w = w * 256;                     // this wave's 256-col strip
  const u32* Bb = nb + (brow + c0w) * (DD / 2);
  bf16x8 ar4[4][4];
  #pragma unroll
  for (int rf = 0; rf < 4; ++rf) {
    const u32* Ap = nb + (long long)(row0 + 16 * rf + m) * (DD / 2) + 4 * q;
    #pragma unroll
    for (int cc = 0; cc < 4; ++cc) ar4[rf][cc] = *(const bf16x8*)(Ap + 16 * cc);
  }
  bf16x8 bcA[4], bcB[4];

#define LOADB2(DST, T) { const u32* p_ = Bb + (long long)(16 * (T) + m) * (DD / 2) + 4 * q; \
  _Pragma("unroll") for (int cc = 0; cc < 4; ++cc) DST[cc] = *(const bf16x8*)(p_ + 16 * cc); }
#define TILEF(BC, T) {                                                             \
    _Pragma("unroll") for (int rf = 0; rf < 4; ++rf) {                             \
      f32x4 acc = z4;                                                              \
      _Pragma("unroll") for (int cc = 0; cc < 4; ++cc)                             \
        acc = __builtin_amdgcn_mfma_f32_16x16x32_bf16(BC[cc], ar4[rf][cc], acc, 0, 0, 0); \
      _Pragma("unroll") for (int p = 0; p < 4; ++p) {                              \
        if (acc[p] >= th4[rf]) {                                                   \
          const u32 id = atomicAdd(&cnt[rib4[rf]], 1u);                            \
          if (id < CAP2) cand[rib4[rf]][id] = (u32)(c0w + 16 * (T) + cof[p]);      \
        }                                                                          \
      }                                                                            \
    } }

  LOADB2(bcA, 0)
  #pragma unroll
  for (int t = 0; t < 16; t += 2) {
    LOADB2(bcB, t + 1)
    TILEF(bcA, t)
    if (t + 2 < 16) LOADB2(bcA, t + 2)
    TILEF(bcB, t + 1)
  }
#undef LOADB2
#undef TILEF
  __syncthreads();

  // ---- Phase C: fp64 rescore (validated R23 16-lane-group) per row + writes ----
  for (int j = 0; j < 8; ++j) {
    const int rib = w * 8 + j;
    const int r = row0 + rib;
    const int n = r & (NN - 1);
    const int c = (int)cnt[rib];
    const double ri = rinv[r];
    u64 kv[8];
    #pragma unroll
    for (int s = 0; s < 8; ++s) kv[s] = 0ull;

    if (c <= CAP2) {
      float2 a4[4];
      #pragma unroll
      for (int jj = 0; jj < 4; ++jj)
        a4[jj] = ((const float2*)(x + (long long)r * DD))[idx_ + 16 * jj];

      for (int i = 0; i < c; i += 4) {
        const int gi = i + s_;
        const bool valid = gi < c;
        const int col = valid ? (int)cand[rib][gi] : 0;
        const float2* cp = (const float2*)(x + (brow + col) * DD);
        double d = 0.0;
        #pragma unroll
        for (int jj = 0; jj < 4; ++jj) {
          const float2 bv = cp[idx_ + 16 * jj];
          d = fma((double)a4[jj].x, (double)bv.x, d);
          d = fma((double)a4[jj].y, (double)bv.y, d);
        }
        #pragma unroll
        for (int mk = 1; mk <= 8; mk <<= 1) d += __shfl_xor(d, mk, 64);
        if (valid) insert8u(kv, make_key(d * ri * rinv[brow + col], col));
      }
      #pragma unroll
      for (int mk = 16; mk <= 32; mk <<= 1) {
        u64 ov[8];
        #pragma unroll
        for (int s = 0; s < 8; ++s) ov[s] = __shfl_xor(kv[s], mk, 64);
        merge8(kv, ov);
      }
    } else {
      // overflow fallback (never expected): full exact row scan (validated)
      for (int base = 0; base < NN; base += 64) {
        const int col = base + l;
        const float* ap = x + (long long)r * DD;
        const float* cp2 = x + (brow + col) * DD;
        double d = 0.0;
        for (int kk = 0; kk < 64; ++kk) {
          const float2 av = ((const float2*)ap)[kk];
          const float2 bv = ((const float2*)cp2)[kk];
          d = fma((double)av.x, (double)bv.x, fma((double)av.y, (double)bv.y, d));
        }
        d = d * ri * rinv[brow + col];
        u64 one[8];
        one[0] = make_key(d, col);
        #pragma unroll
        for (int s = 1; s < 8; ++s) one[s] = 0ull;
        #pragma unroll
        for (int mk = 1; mk <= 32; mk <<= 1) {
          u64 ov[8];
          #pragma unroll
          for (int s = 0; s < 8; ++s) ov[s] = __shfl_xor(one[s], mk, 64);
          merge8(one, ov);
        }
        merge8(kv, one);
      }
    }

    const long long orow = (long long)r * NN;
    const long long obase = brow * NN;         // b*NN*NN
    if (l == 8) out[orow + n] = 1.0f;          // self loop
    #pragma unroll
    for (int s = 0; s < 8; ++s) {
      const int mcol = 2047 - (int)(kv[s] & 2047ull);
      if (l == s) {
        out[orow + mcol] = 1.0f;
        out[obase + (long long)mcol * NN + n] = 1.0f;
      }
    }
  }
}

extern "C" void kernel_launch(void* const* d_in, const int* in_sizes, int n_in,
                              void* d_out, int out_size, void* d_ws, size_t ws_size,
                              hipStream_t stream) {
  const float* x = (const float*)d_in[0];
  float* out = (float*)d_out;
  char* ws = (char*)d_ws;
  u32* nb = (u32*)ws;                                //  4,194,304 B (bf16 normed)
  double* rinv = (double*)(ws + 4194304);            //    131,072 B
  u16* bmaxg = (u16*)(ws + 4325376);                 //  4,194,304 B (16-col block maxes)

  hipLaunchKernelGGL(k_normalize, dim3(NROWS / 4), dim3(256), 0, stream, x, rinv, nb);
  hipLaunchKernelGGL(k_gram_bmax, dim3(1024), dim3(256), 0, stream, nb, bmaxg,
                     (float4*)out);
  hipLaunchKernelGGL(k_topk_fused, dim3(256), dim3(512), 0, stream, nb, bmaxg, x, rinv, out);
}

// Round 8
// 228.576 us; speedup vs baseline: 1.2375x; 1.0661x over previous
//
#include <hip/hip_runtime.h>
#include <cstdint>

#define NN 2048
#define DD 128
#define BATCH 8
#define NROWS 16384
#define MARGIN 0.02f     // need: 2E (fp32-vs-fp64 dot discrepancy) ~= 0.008; 0.02 holds
#define CAP2 48

typedef __attribute__((ext_vector_type(8))) short bf16x8;
typedef __attribute__((ext_vector_type(4))) float f32x4;
typedef unsigned long long u64;
typedef unsigned int u32;
typedef unsigned short u16;

__device__ __forceinline__ u32 bf16rne(float f) {
  u32 u = __float_as_uint(f);
  return (u + 0x7fffu + ((u >> 16) & 1u)) >> 16;
}

// ---------------- K1: norms + bf16 normalized copy (validated R14-R17) + output zero ----------------
// R25: output zero moved here (kernel boundary orders it before k_build's 1.0 writes).
// 4096 blocks x 256 threads = 1,048,576 threads x 8 float4 = 8,388,608 float4 = 134 MB.
__global__ __launch_bounds__(256) void k_normalize(const float* __restrict__ x,
                                                   double* __restrict__ rinv,
                                                   u32* __restrict__ nb,
                                                   float4* __restrict__ outz) {
  const int wave = threadIdx.x >> 6, lane = threadIdx.x & 63;
  const long long row = (long long)blockIdx.x * 4 + wave;   // 16384 rows
  float2 v = ((const float2*)(x + row * DD))[lane];
  const double d0 = v.x, d1 = v.y;
  double s = d0 * d0 + d1 * d1;
  #pragma unroll
  for (int m = 32; m >= 1; m >>= 1) s += __shfl_xor(s, m, 64);
  double den = sqrt(s); den = den > 1e-12 ? den : 1e-12;
  if (lane == 0) rinv[row] = 1.0 / den;
  double2 o; o.x = d0 / den; o.y = d1 / den;
  nb[row * (DD / 2) + lane] = bf16rne((float)o.x) | (bf16rne((float)o.y) << 16);

  // output zero tail
  {
    const int base = blockIdx.x * 256 + threadIdx.x;
    const float4 zf = {0.0f, 0.0f, 0.0f, 0.0f};
    #pragma unroll
    for (int k = 0; k < 8; ++k) outz[base + k * 1048576] = zf;
  }
}

// ---------------- fp32 top-8 machinery: branch-free merge (validated R12/R18) ----------------
#define CXF(i, j) { const float a_ = L[i], b_ = L[j]; L[i] = fmaxf(a_, b_); L[j] = fminf(a_, b_); }
__device__ __forceinline__ void merge8f(float (&kv)[8], const float (&ov)[8]) {
  float L[8];
  #pragma unroll
  for (int i = 0; i < 8; ++i) L[i] = fmaxf(kv[i], ov[7 - i]);
  CXF(0, 4) CXF(1, 5) CXF(2, 6) CXF(3, 7)
  CXF(0, 2) CXF(1, 3) CXF(4, 6) CXF(5, 7)
  CXF(0, 1) CXF(2, 3) CXF(4, 5) CXF(6, 7)
  #pragma unroll
  for (int i = 0; i < 8; ++i) kv[i] = L[i];
}

// ---------------- u64 exact-key machinery (validated R5-R17) ----------------
__device__ __forceinline__ u64 make_key(double s, int col) {
  u64 u = (u64)__double_as_longlong(s);
  const u64 m = (u64)((long long)u >> 63);
  u ^= (m | 0x8000000000000000ull);
  return (u & ~2047ull) | (u64)(2047 - col);
}
__device__ __forceinline__ u64 umax64(u64 a, u64 b) { return a > b ? a : b; }
__device__ __forceinline__ u64 umin64(u64 a, u64 b) { return a > b ? b : a; }
__device__ __forceinline__ void merge8(u64 (&kv)[8], const u64 (&ov)[8]) {
  u64 L[8];
  #pragma unroll
  for (int i = 0; i < 8; ++i) L[i] = umax64(kv[i], ov[7 - i]);
#define CX(i, j) { const u64 a_ = L[i], b_ = L[j]; L[i] = umax64(a_, b_); L[j] = umin64(a_, b_); }
  CX(0, 4) CX(1, 5) CX(2, 6) CX(3, 7)
  CX(0, 2) CX(1, 3) CX(4, 6) CX(5, 7)
  CX(0, 1) CX(2, 3) CX(4, 5) CX(6, 7)
#undef CX
  #pragma unroll
  for (int i = 0; i < 8; ++i) kv[i] = L[i];
}
__device__ __forceinline__ void insert8u(u64 (&v)[8], u64 nk) {
  if (nk > v[7]) {
    v[7] = nk;
    #pragma unroll
    for (int q = 7; q >= 1; --q) {
      const u64 a = v[q - 1], b = v[q];
      const bool sw = b > a;
      v[q - 1] = sw ? b : a; v[q] = sw ? a : b;
    }
  }
}

// ---------------- k_build R25: fully fused bmax + threshold + filter + rescore ----------------
// One workgroup = 64 rows x 2048 cols; 16 waves x private 128-col strip (4 waves/SIMD,
// 2x the latency hiding of the R24 8-wave structure). Pass 1: MFMA all tiles, per-16-col
// block max -> LDS (f32, no bf16 rounding). Phase A: per-row threshold = 8th-largest of
// 128 block maxes - MARGIN (validated butterfly; m8' <= v8 => superset). Pass 2: MFMA
// recompute (bit-identical), filter >= th, push cols. Phase C: validated 16-lane-group
// fp64 rescore + output writes. No score/bmax global traffic at all.
__global__ __launch_bounds__(1024) void k_build(const u32* __restrict__ nb,
                                                const float* __restrict__ x,
                                                const double* __restrict__ rinv,
                                                float* __restrict__ out) {
  __shared__ float bmf[64][130];   // [row][block]+pad: 33 KB; pad 130 -> conflict-free writes
  __shared__ float thl[64];
  __shared__ u32 cnt[64];
  __shared__ u32 cand[64][CAP2];   // 12 KB

  const int tid = threadIdx.x; const int w = tid >> 6; const int l = tid & 63; // w: 0..15
  const int q = l >> 4; const int m = l & 15;
  const int rowblk = blockIdx.x;               // 0..255
  const int row0 = rowblk * 64;
  const int b = rowblk >> 5;
  const long long brow = (long long)b * NN;

  // ---- runtime MFMA layout probe (validated R17) ----
  bf16x8 pvals = {0,0,0,0,0,0,0,0}, pones = {0,0,0,0,0,0,0,0};
  if (q == 0) {
    pvals[0] = (short)(__float_as_uint((float)(m + 1)) >> 16);
    pones[0] = (short)(__float_as_uint(1.0f) >> 16);
  }
  const f32x4 z4 = {0.0f, 0.0f, 0.0f, 0.0f};
  const f32x4 pr  = __builtin_amdgcn_mfma_f32_16x16x32_bf16(pvals, pones, z4, 0, 0, 0);
  const f32x4 pr2 = __builtin_amdgcn_mfma_f32_16x16x32_bf16(pones, pvals, z4, 0, 0, 0);
  int cof[4];
  #pragma unroll
  for (int p = 0; p < 4; ++p) cof[p] = (int)pr[p] - 1;
  const int rof = (int)pr2[0] - 1;

  if (tid < 64) cnt[tid] = 0u;

  // A fragments for all 64 rows (shared across waves; loads hit L1/L2)
  bf16x8 ar4[4][4];
  #pragma unroll
  for (int rf = 0; rf < 4; ++rf) {
    const u32* Ap = nb + (long long)(row0 + 16 * rf + m) * (DD / 2) + 4 * q;
    #pragma unroll
    for (int cc = 0; cc < 4; ++cc) ar4[rf][cc] = *(const bf16x8*)(Ap + 16 * cc);
  }

  const int c0w = w * 128;                     // this wave's private 128-col strip
  const u32* Bb = nb + (brow + c0w) * (DD / 2);
  bf16x8 bcA[4], bcB[4];

#define LOADB(DST, T) { const u32* p_ = Bb + (long long)(16 * (T) + m) * (DD / 2) + 4 * q; \
  _Pragma("unroll") for (int cc = 0; cc < 4; ++cc) DST[cc] = *(const bf16x8*)(p_ + 16 * cc); }

  // ---- Pass 1: block maxes -> LDS ----
#define TILE1(BC, T) {                                                             \
    _Pragma("unroll") for (int rf = 0; rf < 4; ++rf) {                             \
      f32x4 acc = z4;                                                              \
      _Pragma("unroll") for (int cc = 0; cc < 4; ++cc)                             \
        acc = __builtin_amdgcn_mfma_f32_16x16x32_bf16(BC[cc], ar4[rf][cc], acc, 0, 0, 0); \
      float bm_ = fmaxf(fmaxf(acc[0], acc[1]), fmaxf(acc[2], acc[3]));             \
      bm_ = fmaxf(bm_, __shfl_xor(bm_, 16, 64));                                   \
      bm_ = fmaxf(bm_, __shfl_xor(bm_, 32, 64));                                   \
      if (q == 0) bmf[16 * rf + m][w * 8 + (T)] = bm_;                             \
    } }

  LOADB(bcA, 0)
  #pragma unroll
  for (int t = 0; t < 8; t += 2) {
    LOADB(bcB, t + 1)
    TILE1(bcA, t)
    if (t + 2 < 8) LOADB(bcA, t + 2)
    TILE1(bcB, t + 1)
  }
#undef TILE1
  __syncthreads();

  // ---- Phase A: per-row thresholds (validated butterfly), 4 rows per wave ----
  for (int j = 0; j < 4; ++j) {
    const int rib = w * 4 + j;
    const float b0 = bmf[rib][2 * l];
    const float b1 = bmf[rib][2 * l + 1];
    float mx = fmaxf(b0, b1);
    float kv8[8];
    {
      const float o  = __shfl_xor(mx, 1, 64);
      const float h2 = fmaxf(mx, o), l2 = fminf(mx, o);
      const float p0 = __shfl_xor(h2, 2, 64), p1 = __shfl_xor(l2, 2, 64);
      const float m0 = fmaxf(h2, p0);
      const float xx = fminf(h2, p0);
      const float yy = fmaxf(l2, p1);
      const float m3 = fminf(l2, p1);
      const float m1 = fmaxf(xx, yy);
      const float m2 = fminf(xx, yy);
      const float q0 = __shfl_xor(m0, 4, 64), q1 = __shfl_xor(m1, 4, 64);
      const float q2 = __shfl_xor(m2, 4, 64), q3 = __shfl_xor(m3, 4, 64);
      float L[8] = {m0, m1, m2, m3, q3, q2, q1, q0};
      CXF(0, 4) CXF(1, 5) CXF(2, 6) CXF(3, 7)
      CXF(0, 2) CXF(1, 3) CXF(4, 6) CXF(5, 7)
      CXF(0, 1) CXF(2, 3) CXF(4, 5) CXF(6, 7)
      #pragma unroll
      for (int s = 0; s < 8; ++s) kv8[s] = L[s];
      #pragma unroll
      for (int mk = 8; mk <= 32; mk <<= 1) {
        float ov[8];
        #pragma unroll
        for (int s = 0; s < 8; ++s) ov[s] = __shfl_xor(kv8[s], mk, 64);
        merge8f(kv8, ov);
      }
    }
    if (l == 0) thl[rib] = kv8[7] - MARGIN;
  }
  __syncthreads();

  float th4[4]; int rib4[4];
  #pragma unroll
  for (int rf = 0; rf < 4; ++rf) {
    rib4[rf] = 16 * rf + rof;
    th4[rf] = thl[rib4[rf]];
  }

  // ---- Pass 2: MFMA recompute (bit-identical) + filter + push ----
#define TILEF(BC, T) {                                                             \
    _Pragma("unroll") for (int rf = 0; rf < 4; ++rf) {                             \
      f32x4 acc = z4;                                                              \
      _Pragma("unroll") for (int cc = 0; cc < 4; ++cc)                             \
        acc = __builtin_amdgcn_mfma_f32_16x16x32_bf16(BC[cc], ar4[rf][cc], acc, 0, 0, 0); \
      _Pragma("unroll") for (int p = 0; p < 4; ++p) {                              \
        if (acc[p] >= th4[rf]) {                                                   \
          const u32 id = atomicAdd(&cnt[rib4[rf]], 1u);                            \
          if (id < CAP2) cand[rib4[rf]][id] = (u32)(c0w + 16 * (T) + cof[p]);      \
        }                                                                          \
      }                                                                            \
    } }

  LOADB(bcA, 0)
  #pragma unroll
  for (int t = 0; t < 8; t += 2) {
    LOADB(bcB, t + 1)
    TILEF(bcA, t)
    if (t + 2 < 8) LOADB(bcA, t + 2)
    TILEF(bcB, t + 1)
  }
#undef TILEF
#undef LOADB
  __syncthreads();

  // ---- Phase C: fp64 rescore (validated R23 16-lane-group), 4 rows per wave ----
  for (int j = 0; j < 4; ++j) {
    const int rib = w * 4 + j;
    const int r = row0 + rib;
    const int n = r & (NN - 1);
    const int c = (int)cnt[rib];
    const double ri = rinv[r];
    u64 kv[8];
    #pragma unroll
    for (int s = 0; s < 8; ++s) kv[s] = 0ull;

    if (c <= CAP2) {
      float2 a4[4];
      #pragma unroll
      for (int jj = 0; jj < 4; ++jj)
        a4[jj] = ((const float2*)(x + (long long)r * DD))[m + 16 * jj];

      for (int i = 0; i < c; i += 4) {
        const int gi = i + q;
        const bool valid = gi < c;
        const int col = valid ? (int)cand[rib][gi] : 0;
        const float2* cp = (const float2*)(x + (brow + col) * DD);
        double d = 0.0;
        #pragma unroll
        for (int jj = 0; jj < 4; ++jj) {
          const float2 bv = cp[m + 16 * jj];
          d = fma((double)a4[jj].x, (double)bv.x, d);
          d = fma((double)a4[jj].y, (double)bv.y, d);
        }
        #pragma unroll
        for (int mk = 1; mk <= 8; mk <<= 1) d += __shfl_xor(d, mk, 64);
        if (valid) insert8u(kv, make_key(d * ri * rinv[brow + col], col));
      }
      #pragma unroll
      for (int mk = 16; mk <= 32; mk <<= 1) {
        u64 ov[8];
        #pragma unroll
        for (int s = 0; s < 8; ++s) ov[s] = __shfl_xor(kv[s], mk, 64);
        merge8(kv, ov);
      }
    } else {
      // overflow fallback (never expected): full exact row scan (validated)
      for (int base = 0; base < NN; base += 64) {
        const int col = base + l;
        const float* ap = x + (long long)r * DD;
        const float* cp2 = x + (brow + col) * DD;
        double d = 0.0;
        for (int kk = 0; kk < 64; ++kk) {
          const float2 av = ((const float2*)ap)[kk];
          const float2 bv = ((const float2*)cp2)[kk];
          d = fma((double)av.x, (double)bv.x, fma((double)av.y, (double)bv.y, d));
        }
        d = d * ri * rinv[brow + col];
        u64 one[8];
        one[0] = make_key(d, col);
        #pragma unroll
        for (int s = 1; s < 8; ++s) one[s] = 0ull;
        #pragma unroll
        for (int mk = 1; mk <= 32; mk <<= 1) {
          u64 ov[8];
          #pragma unroll
          for (int s = 0; s < 8; ++s) ov[s] = __shfl_xor(one[s], mk, 64);
          merge8(one, ov);
        }
        merge8(kv, one);
      }
    }

    const long long orow = (long long)r * NN;
    const long long obase = brow * NN;         // b*NN*NN
    if (l == 8) out[orow + n] = 1.0f;          // self loop
    #pragma unroll
    for (int s = 0; s < 8; ++s) {
      const int mcol = 2047 - (int)(kv[s] & 2047ull);
      if (l == s) {
        out[orow + mcol] = 1.0f;
        out[obase + (long long)mcol * NN + n] = 1.0f;
      }
    }
  }
}

extern "C" void kernel_launch(void* const* d_in, const int* in_sizes, int n_in,
                              void* d_out, int out_size, void* d_ws, size_t ws_size,
                              hipStream_t stream) {
  const float* x = (const float*)d_in[0];
  float* out = (float*)d_out;
  char* ws = (char*)d_ws;
  u32* nb = (u32*)ws;                                //  4,194,304 B (bf16 normed)
  double* rinv = (double*)(ws + 4194304);            //    131,072 B

  hipLaunchKernelGGL(k_normalize, dim3(NROWS / 4), dim3(256), 0, stream, x, rinv, nb,
                     (float4*)out);
  hipLaunchKernelGGL(k_build, dim3(256), dim3(1024), 0, stream, nb, x, rinv, out);
}